// Round 8
// baseline (1135.439 us; speedup 1.0000x reference)
//
#include <hip/hip_runtime.h>
#include <hip/hip_bf16.h>

#define HID 64
#define NGRAPH 16
#define BN 32            // nodes per bucket
#define MAXNB 2048
#define NCB 256          // count/scatter blocks

// Fixed workspace layout (float offsets) — weights converted to fp32 + folded M,v
enum : int {
  OFF_V      = 1040,
  OFF_M      = 1104,
  OFF_EW1    = 5200,
  OFF_EB1    = 5520,
  OFF_NW1    = 5584,
  OFF_NB1    = 9744,
  OFF_NW2    = 9808,
  OFF_NB2    = 13904,
  OFF_OW1    = 13968,
  OFF_OB1    = 18064,
  OFF_OW2    = 18128,
  OFF_OB2    = 22224,
  OFF_OW3    = 22288,
  OFF_OB3    = 26384,
  OFF_OW4    = 26448,
  OFF_OB4    = 26576,
  OFF_EW2    = 26578,
  OFF_EB2    = 30674,
  OFF_FLAGS  = 30738,                 // 2 ints: [0]=ft (1=bf16), [1]=it (1=int64)
  OFF_PREP   = 30740                  // rep: 8 pooled replicas * 16*64
};

struct WPtrs { const void* p[16]; };

__device__ __forceinline__ float cv(float v) { return v; }
__device__ __forceinline__ float cv(__hip_bfloat16 v) { return __bfloat162float(v); }
// readlane broadcasts (VALU->SGPR, avoids the LDS pipe entirely)
__device__ __forceinline__ float rlf(float v, int k) {
  return __int_as_float(__builtin_amdgcn_readlane(__float_as_int(v), k));
}
__device__ __forceinline__ int rli(int v, int k) {
  return __builtin_amdgcn_readlane(v, k);
}

// ---------------------------------------------------------------------------
// prep: detect dtypes, convert weights to fp32, build folded M, v.
// ---------------------------------------------------------------------------
__global__ __launch_bounds__(256) void prep_kernel(
    const void* xv, const void* eiv, WPtrs wp, float* ws)
{
  __shared__ int red[2];
  __shared__ int s_ft;
  __shared__ float ew2s[4096];
  __shared__ float nw1s[4096];
  const int t = threadIdx.x;

  if (t == 0) { red[0] = 0; red[1] = 0; }
  __syncthreads();
  {
    const unsigned* u = (const unsigned*)xv;
    int big = 0;
    for (int i = t; i < 512; i += 256) {
      const unsigned el = (u[i] >> 7) & 0xFFu;
      big += (el >= 140u) ? 1 : 0;
    }
    atomicAdd(&red[0], big);
  }
  {
    const int* e32 = (const int*)eiv;
    int orv = 0;
    for (int i = 1 + 2 * t; i < 2048; i += 512) orv |= e32[i];
    atomicOr(&red[1], orv);
  }
  __syncthreads();
  if (t == 0) {
    const int ft = (red[0] < 8) ? 1 : 0;
    const int it = (red[1] == 0) ? 1 : 0;
    ((int*)(ws + OFF_FLAGS))[0] = ft;
    ((int*)(ws + OFF_FLAGS))[1] = it;
    s_ft = ft;
  }
  __syncthreads();
  const int ft = s_ft;

  const int sz[16]  = {320,64,4096,64,4160,64,4096,64,4096,64,4096,64,4096,64,128,2};
  const int dst[16] = {OFF_EW1,OFF_EB1,OFF_EW2,OFF_EB2,OFF_NW1,OFF_NB1,OFF_NW2,OFF_NB2,
                       OFF_OW1,OFF_OB1,OFF_OW2,OFF_OB2,OFF_OW3,OFF_OB3,OFF_OW4,OFF_OB4};
  for (int a = 0; a < 16; ++a) {
    const void* src = wp.p[a];
    float* d = ws + dst[a];
    const int n = sz[a];
    for (int i = t; i < n; i += 256)
      d[i] = ft ? __bfloat162float(((const __hip_bfloat16*)src)[i])
                : ((const float*)src)[i];
  }
  __syncthreads();

  for (int i = t; i < 4096; i += 256) {
    ew2s[i] = ws[OFF_EW2 + i];
    nw1s[i] = ws[OFF_NW1 + 64 + i];
  }
  __syncthreads();
  for (int idx = t; idx < 4096; idx += 256) {
    const int i = idx >> 6, j = idx & 63;
    float s = 0.0f;
    #pragma unroll 8
    for (int k = 0; k < 64; ++k)
      s = fmaf(ew2s[i * 64 + k], nw1s[k * 64 + j], s);
    ws[OFF_M + idx] = s;
  }
  for (int j = t; j < 64; j += 256) {
    float s = 0.0f;
    #pragma unroll 8
    for (int k = 0; k < 64; ++k)
      s = fmaf(ws[OFF_EB2 + k], nw1s[k * 64 + j], s);
    ws[OFF_V + j] = s;
  }
}

// ---------------------------------------------------------------------------
// count: per-block LDS histogram; writes gcnt[bucket*NCB + block] (bucket-
// major so the scan's per-bucket chain is one contiguous 1 KB row).
// ---------------------------------------------------------------------------
template<typename IT>
__device__ __forceinline__ void count_impl(
    const IT* __restrict__ ei, int* __restrict__ gcnt, int* lh,
    const int E, const int NB)
{
  const int t = threadIdx.x;
  const int b = blockIdx.x;
  for (int i = t; i < NB; i += 256) lh[i] = 0;
  __syncthreads();
  const int per = (E + NCB - 1) / NCB;
  const int a = b * per;
  const int bnd = (a + per < E) ? (a + per) : E;
  for (int e = a + t; e < bnd; e += 256) {
    const int c = (int)ei[(size_t)E + e];
    atomicAdd(&lh[c >> 5], 1);
  }
  __syncthreads();
  for (int i = t; i < NB; i += 256) gcnt[(size_t)i * NCB + b] = lh[i];
}

__global__ __launch_bounds__(256) void count_kernel(
    const void* eiv, const float* ws, int* gcnt, const int E, const int NB)
{
  __shared__ int lh[MAXNB];
  const int it = ((const int*)(ws + OFF_FLAGS))[1];
  if (it) count_impl<long long>((const long long*)eiv, gcnt, lh, E, NB);
  else    count_impl<int>((const int*)eiv, gcnt, lh, E, NB);
}

// ---------------------------------------------------------------------------
// scan: bucket totals -> exclusive prefix (bstart) -> rewrite gcnt rows to
// absolute per-(bucket,block) start offsets. Single block.
// ---------------------------------------------------------------------------
__global__ __launch_bounds__(256) void scan_kernel(
    int* __restrict__ gcnt, int* __restrict__ bstart, const int NB)
{
  __shared__ int ps[256];
  const int t = threadIdx.x;

  for (int bkt = t; bkt < NB; bkt += 256) {
    int s = 0;
    for (int blk = 0; blk < NCB; ++blk) s += gcnt[(size_t)bkt * NCB + blk];
    bstart[bkt] = s;
  }
  __syncthreads();

  const int seg = (NB + 255) / 256;
  int s = 0;
  for (int i = 0; i < seg; ++i) {
    const int idx = t * seg + i;
    if (idx < NB) s += bstart[idx];
  }
  ps[t] = s;
  __syncthreads();
  for (int off = 1; off < 256; off <<= 1) {
    const int v = (t >= off) ? ps[t - off] : 0;
    __syncthreads();
    ps[t] += v;
    __syncthreads();
  }
  int carry = ps[t] - s;
  for (int i = 0; i < seg; ++i) {
    const int idx = t * seg + i;
    if (idx < NB) {
      const int tot = bstart[idx];
      bstart[idx] = carry;
      int run = carry;
      for (int blk = 0; blk < NCB; ++blk) {
        const int c2 = gcnt[(size_t)idx * NCB + blk];
        gcnt[(size_t)idx * NCB + blk] = run;
        run += c2;
      }
      carry += tot;
    }
  }
  if (t == 255) bstart[NB] = ps[255];
}

// ---------------------------------------------------------------------------
// scatter (per group): write SORTED PAYLOAD records for buckets [gb0,gb1):
//   rec[pos] = (x[row], a0, a1, a2) fp32, cid[pos] = col & 31.
// All source reads are coalesced (ei, ea) or L2-resident (x, 200 KB). LDS
// cursors, zero global atomics, positions group-relative (base=bstart[gb0]).
// ---------------------------------------------------------------------------
template<typename FT, typename IT>
__device__ __forceinline__ void scatter_impl(
    const FT* __restrict__ x, const IT* __restrict__ ei, const FT* __restrict__ ea,
    const int* __restrict__ gcnt, const int* __restrict__ bstart,
    float4* __restrict__ rec, unsigned char* __restrict__ cid, int* lb,
    const int E, const int NB, const int gb0, const int gb1, const int cap)
{
  const int t = threadIdx.x;
  const int b = blockIdx.x;
  __shared__ int sbase;
  if (t == 0) sbase = bstart[gb0];
  __syncthreads();
  const int base = sbase;
  const int gcount = gb1 - gb0;
  for (int i = t; i < gcount; i += 256) lb[i] = gcnt[(size_t)(gb0 + i) * NCB + b] - base;
  __syncthreads();

  const int per = (E + NCB - 1) / NCB;
  const int a = b * per;
  const int bnd = (a + per < E) ? (a + per) : E;
  for (int e = a + t; e < bnd; e += 256) {
    const int c = (int)ei[(size_t)E + e];
    const int bkt = c >> 5;
    if (bkt >= gb0 && bkt < gb1) {
      const int pos = atomicAdd(&lb[bkt - gb0], 1);
      if (pos < cap) {
        const int r = (int)ei[e];
        rec[pos] = make_float4(cv(x[r]), cv(ea[(size_t)3 * e + 0]),
                               cv(ea[(size_t)3 * e + 1]), cv(ea[(size_t)3 * e + 2]));
        cid[pos] = (unsigned char)(c & 31);
      }
    }
  }
}

__global__ __launch_bounds__(256) void scatter_kernel(
    const void* xv, const void* eiv, const void* eav, const float* ws,
    const int* gcnt, const int* bstart, float4* rec, unsigned char* cid,
    const int E, const int NB, const int gb0, const int gb1, const int cap)
{
  __shared__ int lb[MAXNB];
  const int* fl = (const int*)(ws + OFF_FLAGS);
  const int ft = fl[0], it = fl[1];
  if (ft) {
    if (it) scatter_impl<__hip_bfloat16, long long>((const __hip_bfloat16*)xv, (const long long*)eiv, (const __hip_bfloat16*)eav, gcnt, bstart, rec, cid, lb, E, NB, gb0, gb1, cap);
    else    scatter_impl<__hip_bfloat16, int>((const __hip_bfloat16*)xv, (const int*)eiv, (const __hip_bfloat16*)eav, gcnt, bstart, rec, cid, lb, E, NB, gb0, gb1, cap);
  } else {
    if (it) scatter_impl<float, long long>((const float*)xv, (const long long*)eiv, (const float*)eav, gcnt, bstart, rec, cid, lb, E, NB, gb0, gb1, cap);
    else    scatter_impl<float, int>((const float*)xv, (const int*)eiv, (const float*)eav, gcnt, bstart, rec, cid, lb, E, NB, gb0, gb1, cap);
  }
}

// ---------------------------------------------------------------------------
// fused (per group): block owns bucket gb0+blockIdx.x. Waves stream records
// coalesced into registers (lane = edge), consume via readlane broadcasts:
// per edge = 6 readlane + 5 FMA + 1 LDS atomic. Then folded node model and
// pooled accumulation in LDS; tiny replica flush.
// ---------------------------------------------------------------------------
template<typename FT, typename IT>
__device__ __forceinline__ void fused_impl(
    const FT* __restrict__ x, const IT* __restrict__ batch,
    const float* __restrict__ ws, const int* __restrict__ bstart,
    const float4* __restrict__ rec, const unsigned char* __restrict__ cid,
    float* __restrict__ rep,
    float* Msh, float* agg, float* pooledL, float* degL, float* xls, int* gmm,
    const int N, const int gb0, const int cap)
{
  const int t = threadIdx.x;
  const int lane = t & 63;
  const int wav = t >> 6;
  const int bucket = gb0 + blockIdx.x;

  for (int i = t; i < 4096; i += 256) Msh[i] = ws[OFF_M + i];
  for (int i = t; i < BN * 64; i += 256) agg[i] = 0.0f;
  for (int i = t; i < NGRAPH * 64; i += 256) pooledL[i] = 0.0f;
  if (t < BN) {
    degL[t] = 0.0f;
    const int n = bucket * BN + t;
    xls[t] = (n < N) ? cv(x[n]) : 0.0f;
  }
  if (t == 0) { gmm[0] = 1 << 30; gmm[1] = -1; gmm[2] = bstart[gb0]; }
  __syncthreads();

  const float w0 = ws[OFF_EW1 + 0 * HID + lane];
  const float w1 = ws[OFF_EW1 + 1 * HID + lane];
  const float w2 = ws[OFF_EW1 + 2 * HID + lane];
  const float w3 = ws[OFF_EW1 + 3 * HID + lane];
  const float w4 = ws[OFF_EW1 + 4 * HID + lane];
  const float b0 = ws[OFF_EB1 + lane];
  const float xloc = xls[lane & 31];

  const int base = gmm[2];
  int start = bstart[bucket] - base;
  int end   = bstart[bucket + 1] - base;
  if (start > cap) start = cap;
  if (end > cap) end = cap;

  for (int tb = start + wav * 64; tb < end; tb += 256) {
    int m = end - tb; if (m > 64) m = 64;
    const bool val = (lane < m);
    const int idx = tb + (val ? lane : 0);
    const float4 rc = rec[idx];              // coalesced 16B/lane
    const int cL = (int)cid[idx];
    if (val) atomicAdd(&degL[cL], 1.0f);

#define PROC(K) {                                                        \
      const int c = rli(cL, (K));                                        \
      const float xr = rlf(rc.x, (K));                                   \
      const float a0 = rlf(rc.y, (K));                                   \
      const float a1 = rlf(rc.z, (K));                                   \
      const float a2 = rlf(rc.w, (K));                                   \
      const float xc = rlf(xloc, c);                                     \
      float h = fmaf(xr, w0, fmaf(xc, w1,                                \
                fmaf(a0, w2, fmaf(a1, w3, fmaf(a2, w4, b0)))));          \
      h = fmaxf(h, 0.0f);                                                \
      atomicAdd(&agg[c * 64 + lane], h); }

    if (m == 64) {
      #pragma unroll
      for (int k = 0; k < 64; ++k) PROC(k)
    } else {
      for (int k = 0; k < m; ++k) PROC(k)
    }
#undef PROC
  }
  __syncthreads();

  // node model: wave handles 8 nodes
  const float c1 = ws[OFF_NW1 + lane];
  const float bb = ws[OFF_NB1 + lane];
  const float vv = ws[OFF_V + lane];

  for (int i = 0; i < 8; ++i) {
    const int nl = wav * 8 + i;
    const int n = bucket * BN + nl;
    if (n >= N) break;
    const float av = agg[nl * 64 + lane];
    float acc = 0.0f;
    #pragma unroll
    for (int k = 0; k < 64; ++k)
      acc = fmaf(rlf(av, k), Msh[k * 64 + lane], acc);
    const float h = fmaxf(acc + xls[nl] * c1 + degL[nl] * vv + bb, 0.0f);
    const int g = (int)batch[n];
    atomicAdd(&pooledL[g * 64 + lane], h);
    if (lane == 0) { atomicMin(&gmm[0], g); atomicMax(&gmm[1], g); }
  }
  __syncthreads();

  float* myrep = rep + (size_t)(bucket & 7) * (NGRAPH * 64);
  for (int g = gmm[0] + wav; g <= gmm[1]; g += 4)
    unsafeAtomicAdd(&myrep[g * 64 + lane], pooledL[g * 64 + lane]);
}

__global__ __launch_bounds__(256) void fused_kernel(
    const void* xv, const void* batv, const float* ws, const int* bstart,
    const float4* rec, const unsigned char* cid, float* rep,
    const int N, const int gb0, const int cap)
{
  __shared__ float Msh[4096];
  __shared__ float agg[BN * 64];
  __shared__ float pooledL[NGRAPH * 64];
  __shared__ float degL[BN];
  __shared__ float xls[BN];
  __shared__ int   gmm[3];

  const int* fl = (const int*)(ws + OFF_FLAGS);
  const int ft = fl[0], it = fl[1];
  if (ft) {
    if (it) fused_impl<__hip_bfloat16, long long>((const __hip_bfloat16*)xv, (const long long*)batv, ws, bstart, rec, cid, rep, Msh, agg, pooledL, degL, xls, gmm, N, gb0, cap);
    else    fused_impl<__hip_bfloat16, int>((const __hip_bfloat16*)xv, (const int*)batv, ws, bstart, rec, cid, rep, Msh, agg, pooledL, degL, xls, gmm, N, gb0, cap);
  } else {
    if (it) fused_impl<float, long long>((const float*)xv, (const long long*)batv, ws, bstart, rec, cid, rep, Msh, agg, pooledL, degL, xls, gmm, N, gb0, cap);
    else    fused_impl<float, int>((const float*)xv, (const int*)batv, ws, bstart, rec, cid, rep, Msh, agg, pooledL, degL, xls, gmm, N, gb0, cap);
  }
}

// ---------------------------------------------------------------------------
// head: reduce 8 pooled replicas, recompute cnt from batch, then
// pooled@nw2 + cnt*nb2, 3x (Linear+ReLU), Linear(64,2).
// ---------------------------------------------------------------------------
__global__ __launch_bounds__(256) void head_kernel(
    const float* ws, const float* rep, const void* batv, void* outv, const int N)
{
  __shared__ float P[NGRAPH][HID];
  __shared__ float A[NGRAPH][HID];
  __shared__ float B[NGRAPH][HID];
  __shared__ float cntL[NGRAPH];

  const int t = threadIdx.x;
  const int j = t & 63;
  const int gq = t >> 6;

  if (t < NGRAPH) cntL[t] = 0.0f;
  __syncthreads();

  const int it = ((const int*)(ws + OFF_FLAGS))[1];
  if (it) {
    const long long* bt = (const long long*)batv;
    for (int i = t; i < N; i += 256) atomicAdd(&cntL[(int)bt[i]], 1.0f);
  } else {
    const int* bt = (const int*)batv;
    for (int i = t; i < N; i += 256) atomicAdd(&cntL[bt[i]], 1.0f);
  }

  #pragma unroll
  for (int gi = 0; gi < 4; ++gi) {
    const int g = gq + gi * 4;
    float s = 0.0f;
    #pragma unroll
    for (int r = 0; r < 8; ++r)
      s += rep[(size_t)r * (NGRAPH * 64) + g * 64 + j];
    P[g][j] = s;
  }
  __syncthreads();

  {
    const float bj = ws[OFF_NB2 + j];
    #pragma unroll
    for (int gi = 0; gi < 4; ++gi) {
      const int g = gq + gi * 4;
      float s = cntL[g] * bj;
      #pragma unroll 8
      for (int k = 0; k < HID; ++k)
        s = fmaf(P[g][k], ws[OFF_NW2 + k * HID + j], s);
      A[g][j] = s;
    }
  }
  __syncthreads();

  const int wOff[3] = {OFF_OW1, OFF_OW2, OFF_OW3};
  const int bOff[3] = {OFF_OB1, OFF_OB2, OFF_OB3};
  for (int L = 0; L < 3; ++L) {
    float (*In)[HID]  = (L & 1) ? B : A;
    float (*Out)[HID] = (L & 1) ? A : B;
    const float bj = ws[bOff[L] + j];
    #pragma unroll
    for (int gi = 0; gi < 4; ++gi) {
      const int g = gq + gi * 4;
      float s = bj;
      #pragma unroll 8
      for (int k = 0; k < HID; ++k)
        s = fmaf(In[g][k], ws[wOff[L] + k * HID + j], s);
      Out[g][j] = fmaxf(s, 0.0f);
    }
    __syncthreads();
  }

  if (t < 32) {
    const int g = t >> 1, d = t & 1;
    float s = ws[OFF_OB4 + d];
    #pragma unroll 8
    for (int k = 0; k < HID; ++k)
      s = fmaf(B[g][k], ws[OFF_OW4 + k * 2 + d], s);
    const int ft = ((const int*)(ws + OFF_FLAGS))[0];
    if (ft) ((__hip_bfloat16*)outv)[g * 2 + d] = __float2bfloat16(s);
    else    ((float*)outv)[g * 2 + d] = s;
  }
}

extern "C" void kernel_launch(void* const* d_in, const int* in_sizes, int n_in,
                              void* d_out, int out_size, void* d_ws, size_t ws_size,
                              hipStream_t stream)
{
  const void* xv   = d_in[0];
  const void* eiv  = d_in[1];
  const void* eav  = d_in[2];
  const void* batv = d_in[3];

  WPtrs wp;
  for (int a = 0; a < 16; ++a) wp.p[a] = d_in[4 + a];

  const int N = in_sizes[0];
  const int E = in_sizes[1] / 2;
  const int NB = (N + BN - 1) / BN;
  if (NB > MAXNB) return;

  float* ws   = (float*)d_ws;
  float* rep  = ws + OFF_PREP;                             // 8*1024 floats
  int* bstart = (int*)(rep + 8 * NGRAPH * 64);             // NB+1 ints
  int* gcnt   = bstart + NB + 1;                           // NB*NCB ints (bucket-major)

  // record region, 16B aligned
  size_t recOffB = ((size_t)((char*)(gcnt + (size_t)NB * NCB) - (char*)d_ws) + 15) & ~(size_t)15;

  // pick smallest group count G whose records fit the actual workspace
  int G = -1; long long cap = 0;
  for (int g = 1; g <= 64; ++g) {
    const long long c = (long long)E / g + E / 32 + 8192;
    if (recOffB + (size_t)c * 17 <= ws_size) { G = g; cap = c; break; }
  }
  if (G < 0) return;  // diagnostic: zeros output => absmax 6.09375

  float4* rec = (float4*)((char*)d_ws + recOffB);
  unsigned char* cid = (unsigned char*)(rec + cap);
  const int gsz = (NB + G - 1) / G;

  hipMemsetAsync(rep, 0, (size_t)(8 * NGRAPH * 64) * 4, stream);

  prep_kernel<<<1, 256, 0, stream>>>(xv, eiv, wp, ws);
  count_kernel<<<NCB, 256, 0, stream>>>(eiv, ws, gcnt, E, NB);
  scan_kernel<<<1, 256, 0, stream>>>(gcnt, bstart, NB);

  for (int g = 0; g < G; ++g) {
    const int gb0 = g * gsz;
    const int gb1 = (gb0 + gsz < NB) ? (gb0 + gsz) : NB;
    if (gb0 >= gb1) break;
    scatter_kernel<<<NCB, 256, 0, stream>>>(xv, eiv, eav, ws, gcnt, bstart,
                                            rec, cid, E, NB, gb0, gb1, (int)cap);
    fused_kernel<<<gb1 - gb0, 256, 0, stream>>>(xv, batv, ws, bstart, rec, cid,
                                                rep, N, gb0, (int)cap);
  }

  head_kernel<<<1, 256, 0, stream>>>(ws, rep, batv, d_out, N);
}

// Round 9
// 628.379 us; speedup vs baseline: 1.8069x; 1.8069x over previous
//
#include <hip/hip_runtime.h>
#include <hip/hip_bf16.h>

#define HID 64
#define NGRAPH 16
#define BN 32            // nodes per bucket
#define MAXNB 2048
#define NCB 256          // count/scatter blocks

typedef __attribute__((ext_vector_type(8))) short short8;
typedef __attribute__((ext_vector_type(4))) float f32x4;

// Fixed workspace layout (float offsets)
enum : int {
  OFF_V      = 1040,
  OFF_M      = 1104,
  OFF_EW1    = 5200,
  OFF_EB1    = 5520,
  OFF_NW1    = 5584,
  OFF_NB1    = 9744,
  OFF_NW2    = 9808,
  OFF_NB2    = 13904,
  OFF_OW1    = 13968,
  OFF_OB1    = 18064,
  OFF_OW2    = 18128,
  OFF_OB2    = 22224,
  OFF_OW3    = 22288,
  OFF_OB3    = 26384,
  OFF_OW4    = 26448,
  OFF_OB4    = 26576,
  OFF_EW2    = 26578,
  OFF_EB2    = 30674,
  OFF_FLAGS  = 30738,                 // 2 ints: [0]=ft (1=bf16), [1]=it (1=int64)
  OFF_W1T    = 30740,                 // 512 shorts (64 feats x 8 k) = 256 floats
  OFF_MT     = 30996,                 // 4096 shorts (M^T bf16)      = 2048 floats
  OFF_PREP   = 33044                  // rep: 8 pooled replicas * 16*64
};

struct WPtrs { const void* p[16]; };

__device__ __forceinline__ float cv(float v) { return v; }
__device__ __forceinline__ float cv(__hip_bfloat16 v) { return __bfloat162float(v); }
__device__ __forceinline__ unsigned short f2bu(float v) {
  union { __hip_bfloat16 b; unsigned short u; } c;
  c.b = __float2bfloat16(v);
  return c.u;
}

// ---------------------------------------------------------------------------
// prep: detect dtypes, convert weights to fp32, build folded M, v, and the
// MFMA-ready bf16 tables W1T[feat][k] (k: 0..4=ew1 rows, 5=eb1, 6,7=0) and
// MT[feat][k] = bf16(M[k][feat]).
// ---------------------------------------------------------------------------
__global__ __launch_bounds__(256) void prep_kernel(
    const void* xv, const void* eiv, WPtrs wp, float* ws)
{
  __shared__ int red[2];
  __shared__ int s_ft;
  __shared__ float ew2s[4096];
  __shared__ float nw1s[4096];
  const int t = threadIdx.x;

  if (t == 0) { red[0] = 0; red[1] = 0; }
  __syncthreads();
  {
    const unsigned* u = (const unsigned*)xv;
    int big = 0;
    for (int i = t; i < 512; i += 256) {
      const unsigned el = (u[i] >> 7) & 0xFFu;
      big += (el >= 140u) ? 1 : 0;
    }
    atomicAdd(&red[0], big);
  }
  {
    const int* e32 = (const int*)eiv;
    int orv = 0;
    for (int i = 1 + 2 * t; i < 2048; i += 512) orv |= e32[i];
    atomicOr(&red[1], orv);
  }
  __syncthreads();
  if (t == 0) {
    const int ft = (red[0] < 8) ? 1 : 0;
    const int it = (red[1] == 0) ? 1 : 0;
    ((int*)(ws + OFF_FLAGS))[0] = ft;
    ((int*)(ws + OFF_FLAGS))[1] = it;
    s_ft = ft;
  }
  __syncthreads();
  const int ft = s_ft;

  const int sz[16]  = {320,64,4096,64,4160,64,4096,64,4096,64,4096,64,4096,64,128,2};
  const int dst[16] = {OFF_EW1,OFF_EB1,OFF_EW2,OFF_EB2,OFF_NW1,OFF_NB1,OFF_NW2,OFF_NB2,
                       OFF_OW1,OFF_OB1,OFF_OW2,OFF_OB2,OFF_OW3,OFF_OB3,OFF_OW4,OFF_OB4};
  for (int a = 0; a < 16; ++a) {
    const void* src = wp.p[a];
    float* d = ws + dst[a];
    const int n = sz[a];
    for (int i = t; i < n; i += 256)
      d[i] = ft ? __bfloat162float(((const __hip_bfloat16*)src)[i])
                : ((const float*)src)[i];
  }
  __syncthreads();

  for (int i = t; i < 4096; i += 256) {
    ew2s[i] = ws[OFF_EW2 + i];
    nw1s[i] = ws[OFF_NW1 + 64 + i];
  }
  __syncthreads();
  for (int idx = t; idx < 4096; idx += 256) {
    const int i = idx >> 6, j = idx & 63;
    float s = 0.0f;
    #pragma unroll 8
    for (int k = 0; k < 64; ++k)
      s = fmaf(ew2s[i * 64 + k], nw1s[k * 64 + j], s);
    ws[OFF_M + idx] = s;
  }
  for (int j = t; j < 64; j += 256) {
    float s = 0.0f;
    #pragma unroll 8
    for (int k = 0; k < 64; ++k)
      s = fmaf(ws[OFF_EB2 + k], nw1s[k * 64 + j], s);
    ws[OFF_V + j] = s;
  }
  __syncthreads();

  // W1T: [n][k] k<5 -> ew1[k][n], k==5 -> eb1[n], else 0
  unsigned short* w1t = (unsigned short*)(ws + OFF_W1T);
  for (int n = t; n < 64; n += 256) {
    #pragma unroll
    for (int k = 0; k < 8; ++k) {
      float v = 0.0f;
      if (k < 5) v = ws[OFF_EW1 + k * 64 + n];
      else if (k == 5) v = ws[OFF_EB1 + n];
      w1t[n * 8 + k] = f2bu(v);
    }
  }
  // MT: [n][k] = bf16(M[k][n])
  unsigned short* mt = (unsigned short*)(ws + OFF_MT);
  for (int idx = t; idx < 4096; idx += 256) {
    const int n = idx >> 6, k = idx & 63;
    mt[idx] = f2bu(ws[OFF_M + k * 64 + n]);
  }
}

// ---------------------------------------------------------------------------
// count: per-block LDS histogram; gcnt[bucket*NCB + block] (bucket-major).
// ---------------------------------------------------------------------------
template<typename IT>
__device__ __forceinline__ void count_impl(
    const IT* __restrict__ ei, int* __restrict__ gcnt, int* lh,
    const int E, const int NB)
{
  const int t = threadIdx.x;
  const int b = blockIdx.x;
  for (int i = t; i < NB; i += 256) lh[i] = 0;
  __syncthreads();
  const int per = (E + NCB - 1) / NCB;
  const int a = b * per;
  const int bnd = (a + per < E) ? (a + per) : E;
  for (int e = a + t; e < bnd; e += 256) {
    const int c = (int)ei[(size_t)E + e];
    atomicAdd(&lh[c >> 5], 1);
  }
  __syncthreads();
  for (int i = t; i < NB; i += 256) gcnt[(size_t)i * NCB + b] = lh[i];
}

__global__ __launch_bounds__(256) void count_kernel(
    const void* eiv, const float* ws, int* gcnt, const int E, const int NB)
{
  __shared__ int lh[MAXNB];
  const int it = ((const int*)(ws + OFF_FLAGS))[1];
  if (it) count_impl<long long>((const long long*)eiv, gcnt, lh, E, NB);
  else    count_impl<int>((const int*)eiv, gcnt, lh, E, NB);
}

// ---------------------------------------------------------------------------
// scan: bucket totals -> exclusive prefix (bstart) -> absolute offsets.
// ---------------------------------------------------------------------------
__global__ __launch_bounds__(256) void scan_kernel(
    int* __restrict__ gcnt, int* __restrict__ bstart, const int NB)
{
  __shared__ int ps[256];
  const int t = threadIdx.x;

  for (int bkt = t; bkt < NB; bkt += 256) {
    int s = 0;
    for (int blk = 0; blk < NCB; ++blk) s += gcnt[(size_t)bkt * NCB + blk];
    bstart[bkt] = s;
  }
  __syncthreads();

  const int seg = (NB + 255) / 256;
  int s = 0;
  for (int i = 0; i < seg; ++i) {
    const int idx = t * seg + i;
    if (idx < NB) s += bstart[idx];
  }
  ps[t] = s;
  __syncthreads();
  for (int off = 1; off < 256; off <<= 1) {
    const int v = (t >= off) ? ps[t - off] : 0;
    __syncthreads();
    ps[t] += v;
    __syncthreads();
  }
  int carry = ps[t] - s;
  for (int i = 0; i < seg; ++i) {
    const int idx = t * seg + i;
    if (idx < NB) {
      const int tot = bstart[idx];
      bstart[idx] = carry;
      int run = carry;
      for (int blk = 0; blk < NCB; ++blk) {
        const int c2 = gcnt[(size_t)idx * NCB + blk];
        gcnt[(size_t)idx * NCB + blk] = run;
        run += c2;
      }
      carry += tot;
    }
  }
  if (t == 255) bstart[NB] = ps[255];
}

// ---------------------------------------------------------------------------
// scatter (per group): write sorted bf16 payload recB[pos]={xr,a0,a1,a2} +
// cid[pos]=col&31 for buckets [gb0,gb1). LDS cursors; zero global atomics.
// Param order (ei,gcnt,lb,seid-like...) kept straight (r6 lesson).
// ---------------------------------------------------------------------------
template<typename FT, typename IT>
__device__ __forceinline__ void scatter_impl(
    const FT* __restrict__ x, const IT* __restrict__ ei, const FT* __restrict__ ea,
    const int* __restrict__ gcnt, const int* __restrict__ bstart,
    ushort4* __restrict__ recB, unsigned char* __restrict__ cid, int* lb,
    const int E, const int NB, const int gb0, const int gb1, const int cap)
{
  const int t = threadIdx.x;
  const int b = blockIdx.x;
  __shared__ int sbase;
  if (t == 0) sbase = bstart[gb0];
  __syncthreads();
  const int base = sbase;
  const int gcount = gb1 - gb0;
  for (int i = t; i < gcount; i += 256) lb[i] = gcnt[(size_t)(gb0 + i) * NCB + b] - base;
  __syncthreads();

  const int per = (E + NCB - 1) / NCB;
  const int a = b * per;
  const int bnd = (a + per < E) ? (a + per) : E;
  for (int e = a + t; e < bnd; e += 256) {
    const int c = (int)ei[(size_t)E + e];
    const int bkt = c >> 5;
    if (bkt >= gb0 && bkt < gb1) {
      const int pos = atomicAdd(&lb[bkt - gb0], 1);
      if (pos < cap) {
        const int r = (int)ei[e];
        ushort4 rv;
        rv.x = f2bu(cv(x[r]));
        rv.y = f2bu(cv(ea[(size_t)3 * e + 0]));
        rv.z = f2bu(cv(ea[(size_t)3 * e + 1]));
        rv.w = f2bu(cv(ea[(size_t)3 * e + 2]));
        recB[pos] = rv;
        cid[pos] = (unsigned char)(c & 31);
      }
    }
  }
}

__global__ __launch_bounds__(256) void scatter_kernel(
    const void* xv, const void* eiv, const void* eav, const float* ws,
    const int* gcnt, const int* bstart, ushort4* recB, unsigned char* cid,
    const int E, const int NB, const int gb0, const int gb1, const int cap)
{
  __shared__ int lb[MAXNB];
  const int* fl = (const int*)(ws + OFF_FLAGS);
  const int ft = fl[0], it = fl[1];
  if (ft) {
    if (it) scatter_impl<__hip_bfloat16, long long>((const __hip_bfloat16*)xv, (const long long*)eiv, (const __hip_bfloat16*)eav, gcnt, bstart, recB, cid, lb, E, NB, gb0, gb1, cap);
    else    scatter_impl<__hip_bfloat16, int>((const __hip_bfloat16*)xv, (const int*)eiv, (const __hip_bfloat16*)eav, gcnt, bstart, recB, cid, lb, E, NB, gb0, gb1, cap);
  } else {
    if (it) scatter_impl<float, long long>((const float*)xv, (const long long*)eiv, (const float*)eav, gcnt, bstart, recB, cid, lb, E, NB, gb0, gb1, cap);
    else    scatter_impl<float, int>((const float*)xv, (const int*)eiv, (const float*)eav, gcnt, bstart, recB, cid, lb, E, NB, gb0, gb1, cap);
  }
}

// ---------------------------------------------------------------------------
// fused (MFMA): block owns bucket gb0+blockIdx.x (32 nodes, ~1024 edges).
// Per wave-owned 64-edge tile:
//   GEMM1: H = relu(A[64x32] @ W1)       (A cols: xr,xc,a0,a1,a2,1; eb1 folded)
//   GEMM2: agg += S[32x64] @ H ; deg += S @ ones   (S from sorted cids)
// Then node GEMM: h_pre = agg @ M; epilogue + pooled accumulation.
// MFMA layouts (16x16x32 bf16): A[m=lane&15][k=(lane>>4)*8+j],
// B[k=(lane>>4)*8+j][n=lane&15], C/D[row=(lane>>4)*4+reg][col=lane&15].
// ---------------------------------------------------------------------------
template<typename FT, typename IT>
__device__ __forceinline__ void fused_impl(
    const FT* __restrict__ x, const IT* __restrict__ batch,
    const float* __restrict__ ws, const int* __restrict__ bstart,
    const ushort4* __restrict__ recB, const unsigned char* __restrict__ cid,
    float* __restrict__ rep,
    short* sA, unsigned char* scid, short* sHT, float* aggF,
    float* pooledL, float* xls, int* sbi,
    const int N, const int gb0, const int cap)
{
  const int t = threadIdx.x;
  const int lane = t & 63;
  const int quad = lane >> 4;
  const int l15 = lane & 15;
  const int wav = t >> 6;
  const int bucket = gb0 + blockIdx.x;

  // zero aggF (32x68) and pooledL (16x64)
  for (int i = t; i < 32 * 68; i += 256) aggF[i] = 0.0f;
  for (int i = t; i < NGRAPH * 64; i += 256) pooledL[i] = 0.0f;
  if (t < BN) {
    const int n = bucket * BN + t;
    xls[t] = (n < N) ? cv(x[n]) : 0.0f;
  }
  if (t == 0) {
    const int nf = bucket * BN, nl = bucket * BN + BN - 1;
    sbi[0] = (int)batch[(nf < N) ? nf : (N - 1)];
    sbi[1] = (int)batch[(nl < N) ? nl : (N - 1)];
    sbi[2] = bstart[gb0];
  }
  __syncthreads();

  // b1 fragments (W1: rows k<8 only; lanes quad>0 carry zeros)
  const unsigned short* w1t = (const unsigned short*)(ws + OFF_W1T);
  short8 B1[4];
  #pragma unroll
  for (int tn = 0; tn < 4; ++tn) {
    short8 z; for (int j = 0; j < 8; ++j) z[j] = 0;
    if (quad == 0) z = *(const short8*)(w1t + (16 * tn + l15) * 8);
    B1[tn] = z;
  }
  short8 ONES8;
  #pragma unroll
  for (int j = 0; j < 8; ++j) ONES8[j] = (short)0x3F80;

  const int base = sbi[2];
  int s0 = bstart[bucket] - base;
  int e0 = bstart[bucket + 1] - base;
  if (s0 > cap) s0 = cap;
  if (e0 > cap) e0 = cap;

  f32x4 C2[2][4];
  f32x4 C3[2];
  #pragma unroll
  for (int i = 0; i < 2; ++i) {
    #pragma unroll
    for (int j2 = 0; j2 < 4; ++j2) { C2[i][j2] = (f32x4)0.0f; }
    C3[i] = (f32x4)0.0f;
  }

  short* mysA = sA + wav * 64 * 8;
  unsigned char* myscid = scid + wav * 64;
  short* mysHT = sHT + wav * 64 * 72;

  const int ntile = (e0 - s0 + 63) >> 6;
  for (int tt = wav; tt < ntile; tt += 4) {
    const int eb = s0 + tt * 64;
    const int idx = eb + lane;
    const bool valid = idx < e0;
    ushort4 rv = valid ? recB[idx] : make_ushort4(0, 0, 0, 0);
    const int c = valid ? (int)cid[idx] : 255;
    const unsigned short xcb = valid ? f2bu(xls[c]) : (unsigned short)0;

    short8 row;
    row[0] = (short)rv.x; row[1] = (short)xcb;
    row[2] = (short)rv.y; row[3] = (short)rv.z; row[4] = (short)rv.w;
    row[5] = valid ? (short)0x3F80 : (short)0;  // constant-1 col -> eb1
    row[6] = 0; row[7] = 0;
    *(short8*)(mysA + lane * 8) = row;
    myscid[lane] = (unsigned char)c;

    // GEMM1: H tiles
    f32x4 Hc[4][4];
    #pragma unroll
    for (int tm = 0; tm < 4; ++tm) {
      short8 a1;
      if (quad == 0) a1 = *(const short8*)(mysA + (16 * tm + l15) * 8);
      else { for (int j = 0; j < 8; ++j) a1[j] = 0; }
      #pragma unroll
      for (int tn = 0; tn < 4; ++tn)
        Hc[tm][tn] = __builtin_amdgcn_mfma_f32_16x16x32_bf16(a1, B1[tn], (f32x4)0.0f, 0, 0, 0);
    }
    // relu + dump H^T (bf16, [feat][edge], stride 72 shorts)
    #pragma unroll
    for (int tm = 0; tm < 4; ++tm) {
      #pragma unroll
      for (int tn = 0; tn < 4; ++tn) {
        unsigned short u0 = f2bu(fmaxf(Hc[tm][tn][0], 0.0f));
        unsigned short u1 = f2bu(fmaxf(Hc[tm][tn][1], 0.0f));
        unsigned short u2 = f2bu(fmaxf(Hc[tm][tn][2], 0.0f));
        unsigned short u3 = f2bu(fmaxf(Hc[tm][tn][3], 0.0f));
        uint2 pk;
        pk.x = (unsigned)u0 | ((unsigned)u1 << 16);
        pk.y = (unsigned)u2 | ((unsigned)u3 << 16);
        *(uint2*)(mysHT + (16 * tn + l15) * 72 + 16 * tm + quad * 4) = pk;
      }
    }
    // GEMM2: agg += S @ H ; deg += S @ 1
    const unsigned* sp = (const unsigned*)myscid;
    #pragma unroll
    for (int q = 0; q < 2; ++q) {
      const unsigned lo = sp[2 * quad + 8 * q];
      const unsigned hi = sp[2 * quad + 8 * q + 1];
      short8 a2[2];
      #pragma unroll
      for (int tm2 = 0; tm2 < 2; ++tm2) {
        const int seg = 16 * tm2 + l15;
        short8 v;
        v[0] = (((lo      ) & 255u) == (unsigned)seg) ? (short)0x3F80 : (short)0;
        v[1] = (((lo >>  8) & 255u) == (unsigned)seg) ? (short)0x3F80 : (short)0;
        v[2] = (((lo >> 16) & 255u) == (unsigned)seg) ? (short)0x3F80 : (short)0;
        v[3] = (((lo >> 24) & 255u) == (unsigned)seg) ? (short)0x3F80 : (short)0;
        v[4] = (((hi      ) & 255u) == (unsigned)seg) ? (short)0x3F80 : (short)0;
        v[5] = (((hi >>  8) & 255u) == (unsigned)seg) ? (short)0x3F80 : (short)0;
        v[6] = (((hi >> 16) & 255u) == (unsigned)seg) ? (short)0x3F80 : (short)0;
        v[7] = (((hi >> 24) & 255u) == (unsigned)seg) ? (short)0x3F80 : (short)0;
        a2[tm2] = v;
      }
      #pragma unroll
      for (int tn2 = 0; tn2 < 4; ++tn2) {
        const short8 b2 = *(const short8*)(mysHT + (16 * tn2 + l15) * 72 + 32 * q + quad * 8);
        #pragma unroll
        for (int tm2 = 0; tm2 < 2; ++tm2)
          C2[tm2][tn2] = __builtin_amdgcn_mfma_f32_16x16x32_bf16(a2[tm2], b2, C2[tm2][tn2], 0, 0, 0);
      }
      #pragma unroll
      for (int tm2 = 0; tm2 < 2; ++tm2)
        C3[tm2] = __builtin_amdgcn_mfma_f32_16x16x32_bf16(a2[tm2], ONES8, C3[tm2], 0, 0, 0);
    }
  }

  // cross-wave reduce into aggF
  __syncthreads();
  #pragma unroll
  for (int tm2 = 0; tm2 < 2; ++tm2) {
    #pragma unroll
    for (int tn2 = 0; tn2 < 4; ++tn2) {
      #pragma unroll
      for (int r = 0; r < 4; ++r)
        atomicAdd(&aggF[(16 * tm2 + quad * 4 + r) * 68 + 16 * tn2 + l15], C2[tm2][tn2][r]);
    }
    if (l15 == 0) {
      #pragma unroll
      for (int r = 0; r < 4; ++r)
        atomicAdd(&aggF[(16 * tm2 + quad * 4 + r) * 68 + 64], C3[tm2][r]);
    }
  }
  __syncthreads();

  // node GEMM: wave w handles feature-tile tn=w. D[32x16] = agg @ M (bf16)
  const unsigned short* mt = (const unsigned short*)(ws + OFF_MT);
  f32x4 D[2];
  D[0] = (f32x4)0.0f; D[1] = (f32x4)0.0f;
  #pragma unroll
  for (int q = 0; q < 2; ++q) {
    const short8 bb = *(const short8*)(mt + (16 * wav + l15) * 64 + 32 * q + quad * 8);
    #pragma unroll
    for (int tm2 = 0; tm2 < 2; ++tm2) {
      const float4 p0 = *(const float4*)(&aggF[(16 * tm2 + l15) * 68 + quad * 8 + 32 * q]);
      const float4 p1 = *(const float4*)(&aggF[(16 * tm2 + l15) * 68 + quad * 8 + 32 * q + 4]);
      short8 aa;
      aa[0] = (short)f2bu(p0.x); aa[1] = (short)f2bu(p0.y);
      aa[2] = (short)f2bu(p0.z); aa[3] = (short)f2bu(p0.w);
      aa[4] = (short)f2bu(p1.x); aa[5] = (short)f2bu(p1.y);
      aa[6] = (short)f2bu(p1.z); aa[7] = (short)f2bu(p1.w);
      D[tm2] = __builtin_amdgcn_mfma_f32_16x16x32_bf16(aa, bb, D[tm2], 0, 0, 0);
    }
  }

  // epilogue: h = relu(D + x*c1 + deg*v + nb1); pool by graph
  const int n = 16 * wav + l15;       // feature col
  const float c1n = ws[OFF_NW1 + n];
  const float vn  = ws[OFF_V + n];
  const float bn  = ws[OFF_NB1 + n];
  #pragma unroll
  for (int tm2 = 0; tm2 < 2; ++tm2) {
    #pragma unroll
    for (int r = 0; r < 4; ++r) {
      const int m = 16 * tm2 + quad * 4 + r;
      const int ng = bucket * BN + m;
      if (ng < N) {
        const float deg = aggF[m * 68 + 64];
        const float h = fmaxf(D[tm2][r] + xls[m] * c1n + deg * vn + bn, 0.0f);
        const int g = (int)batch[ng];
        atomicAdd(&pooledL[g * 64 + n], h);
      }
    }
  }
  __syncthreads();

  float* myrep = rep + (size_t)(bucket & 7) * (NGRAPH * 64);
  for (int g = sbi[0] + wav; g <= sbi[1]; g += 4)
    unsafeAtomicAdd(&myrep[g * 64 + lane], pooledL[g * 64 + lane]);
}

__global__ __launch_bounds__(256) void fused_kernel(
    const void* xv, const void* batv, const float* ws, const int* bstart,
    const ushort4* recB, const unsigned char* cid, float* rep,
    const int N, const int gb0, const int cap)
{
  // All LDS hoisted here (one copy across template instantiations).
  __shared__ __align__(16) short sA[4 * 64 * 8];         // 4 KB
  __shared__ __align__(8)  unsigned char scid[4 * 64];   // 256 B
  __shared__ __align__(16) short sHT[4 * 64 * 72];       // 36.9 KB
  __shared__ __align__(16) float aggF[32 * 68];          // 8.7 KB
  __shared__ float pooledL[NGRAPH * 64];                 // 4 KB
  __shared__ float xls[BN];
  __shared__ int   sbi[3];

  const int* fl = (const int*)(ws + OFF_FLAGS);
  const int ft = fl[0], it = fl[1];
  if (ft) {
    if (it) fused_impl<__hip_bfloat16, long long>((const __hip_bfloat16*)xv, (const long long*)batv, ws, bstart, recB, cid, rep, sA, scid, sHT, aggF, pooledL, xls, sbi, N, gb0, cap);
    else    fused_impl<__hip_bfloat16, int>((const __hip_bfloat16*)xv, (const int*)batv, ws, bstart, recB, cid, rep, sA, scid, sHT, aggF, pooledL, xls, sbi, N, gb0, cap);
  } else {
    if (it) fused_impl<float, long long>((const float*)xv, (const long long*)batv, ws, bstart, recB, cid, rep, sA, scid, sHT, aggF, pooledL, xls, sbi, N, gb0, cap);
    else    fused_impl<float, int>((const float*)xv, (const int*)batv, ws, bstart, recB, cid, rep, sA, scid, sHT, aggF, pooledL, xls, sbi, N, gb0, cap);
  }
}

// ---------------------------------------------------------------------------
// head: reduce 8 pooled replicas, recompute cnt from batch, dense head.
// ---------------------------------------------------------------------------
__global__ __launch_bounds__(256) void head_kernel(
    const float* ws, const float* rep, const void* batv, void* outv, const int N)
{
  __shared__ float P[NGRAPH][HID];
  __shared__ float A[NGRAPH][HID];
  __shared__ float B[NGRAPH][HID];
  __shared__ float cntL[NGRAPH];

  const int t = threadIdx.x;
  const int j = t & 63;
  const int gq = t >> 6;

  if (t < NGRAPH) cntL[t] = 0.0f;
  __syncthreads();

  const int it = ((const int*)(ws + OFF_FLAGS))[1];
  if (it) {
    const long long* bt = (const long long*)batv;
    for (int i = t; i < N; i += 256) atomicAdd(&cntL[(int)bt[i]], 1.0f);
  } else {
    const int* bt = (const int*)batv;
    for (int i = t; i < N; i += 256) atomicAdd(&cntL[bt[i]], 1.0f);
  }

  #pragma unroll
  for (int gi = 0; gi < 4; ++gi) {
    const int g = gq + gi * 4;
    float s = 0.0f;
    #pragma unroll
    for (int r = 0; r < 8; ++r)
      s += rep[(size_t)r * (NGRAPH * 64) + g * 64 + j];
    P[g][j] = s;
  }
  __syncthreads();

  {
    const float bj = ws[OFF_NB2 + j];
    #pragma unroll
    for (int gi = 0; gi < 4; ++gi) {
      const int g = gq + gi * 4;
      float s = cntL[g] * bj;
      #pragma unroll 8
      for (int k = 0; k < HID; ++k)
        s = fmaf(P[g][k], ws[OFF_NW2 + k * HID + j], s);
      A[g][j] = s;
    }
  }
  __syncthreads();

  const int wOff[3] = {OFF_OW1, OFF_OW2, OFF_OW3};
  const int bOff[3] = {OFF_OB1, OFF_OB2, OFF_OB3};
  for (int L = 0; L < 3; ++L) {
    float (*In)[HID]  = (L & 1) ? B : A;
    float (*Out)[HID] = (L & 1) ? A : B;
    const float bj = ws[bOff[L] + j];
    #pragma unroll
    for (int gi = 0; gi < 4; ++gi) {
      const int g = gq + gi * 4;
      float s = bj;
      #pragma unroll 8
      for (int k = 0; k < HID; ++k)
        s = fmaf(In[g][k], ws[wOff[L] + k * HID + j], s);
      Out[g][j] = fmaxf(s, 0.0f);
    }
    __syncthreads();
  }

  if (t < 32) {
    const int g = t >> 1, d = t & 1;
    float s = ws[OFF_OB4 + d];
    #pragma unroll 8
    for (int k = 0; k < HID; ++k)
      s = fmaf(B[g][k], ws[OFF_OW4 + k * 2 + d], s);
    const int ft = ((const int*)(ws + OFF_FLAGS))[0];
    if (ft) ((__hip_bfloat16*)outv)[g * 2 + d] = __float2bfloat16(s);
    else    ((float*)outv)[g * 2 + d] = s;
  }
}

extern "C" void kernel_launch(void* const* d_in, const int* in_sizes, int n_in,
                              void* d_out, int out_size, void* d_ws, size_t ws_size,
                              hipStream_t stream)
{
  const void* xv   = d_in[0];
  const void* eiv  = d_in[1];
  const void* eav  = d_in[2];
  const void* batv = d_in[3];

  WPtrs wp;
  for (int a = 0; a < 16; ++a) wp.p[a] = d_in[4 + a];

  const int N = in_sizes[0];
  const int E = in_sizes[1] / 2;
  const int NB = (N + BN - 1) / BN;
  if (NB > MAXNB) return;

  float* ws   = (float*)d_ws;
  float* rep  = ws + OFF_PREP;                             // 8*1024 floats
  int* bstart = (int*)(rep + 8 * NGRAPH * 64);             // NB+1 ints
  int* gcnt   = bstart + NB + 1;                           // NB*NCB ints

  size_t recOffB = ((size_t)((char*)(gcnt + (size_t)NB * NCB) - (char*)d_ws) + 15) & ~(size_t)15;

  // pick smallest group count G whose bf16 records (8B) + cid (1B) fit
  int G = -1; long long cap = 0;
  for (int g = 1; g <= 64; ++g) {
    const long long c = (long long)E / g + E / 32 + 8192;
    if (recOffB + (size_t)c * 9 <= ws_size) { G = g; cap = c; break; }
  }
  if (G < 0) return;  // diagnostic: zeros output => absmax 6.09375

  ushort4* recB = (ushort4*)((char*)d_ws + recOffB);
  unsigned char* cid = (unsigned char*)(recB + cap);
  const int gsz = (NB + G - 1) / G;

  hipMemsetAsync(rep, 0, (size_t)(8 * NGRAPH * 64) * 4, stream);

  prep_kernel<<<1, 256, 0, stream>>>(xv, eiv, wp, ws);
  count_kernel<<<NCB, 256, 0, stream>>>(eiv, ws, gcnt, E, NB);
  scan_kernel<<<1, 256, 0, stream>>>(gcnt, bstart, NB);

  for (int g = 0; g < G; ++g) {
    const int gb0 = g * gsz;
    const int gb1 = (gb0 + gsz < NB) ? (gb0 + gsz) : NB;
    if (gb0 >= gb1) break;
    scatter_kernel<<<NCB, 256, 0, stream>>>(xv, eiv, eav, ws, gcnt, bstart,
                                            recB, cid, E, NB, gb0, gb1, (int)cap);
    fused_kernel<<<gb1 - gb0, 256, 0, stream>>>(xv, batv, ws, bstart, recB, cid,
                                                rep, N, gb0, (int)cap);
  }

  head_kernel<<<1, 256, 0, stream>>>(ws, rep, batv, d_out, N);
}

// Round 10
// 466.057 us; speedup vs baseline: 2.4363x; 1.3483x over previous
//
#include <hip/hip_runtime.h>
#include <hip/hip_bf16.h>

#define HID 64
#define NGRAPH 16
#define BN 32            // nodes per bucket
#define MAXNB 2048
#define NCB 256          // count/scatter blocks

typedef __attribute__((ext_vector_type(8))) short short8;
typedef __attribute__((ext_vector_type(4))) float f32x4;

// Fixed workspace layout (float offsets)
enum : int {
  OFF_V      = 1040,
  OFF_M      = 1104,
  OFF_EW1    = 5200,
  OFF_EB1    = 5520,
  OFF_NW1    = 5584,
  OFF_NB1    = 9744,
  OFF_NW2    = 9808,
  OFF_NB2    = 13904,
  OFF_OW1    = 13968,
  OFF_OB1    = 18064,
  OFF_OW2    = 18128,
  OFF_OB2    = 22224,
  OFF_OW3    = 22288,
  OFF_OB3    = 26384,
  OFF_OW4    = 26448,
  OFF_OB4    = 26576,
  OFF_EW2    = 26578,
  OFF_EB2    = 30674,
  OFF_FLAGS  = 30738,                 // 2 ints: [0]=ft (1=bf16), [1]=it (1=int64)
  OFF_W1T    = 30740,                 // 512 shorts (64 feats x 8 k) = 256 floats
  OFF_MT     = 30996,                 // 4096 shorts (M^T bf16)      = 2048 floats
  OFF_PREP   = 33044                  // rep: 8 pooled replicas * 16*64
};

struct WPtrs { const void* p[16]; };

__device__ __forceinline__ float cv(float v) { return v; }
__device__ __forceinline__ float cv(__hip_bfloat16 v) { return __bfloat162float(v); }
__device__ __forceinline__ unsigned short f2bu(float v) {
  union { __hip_bfloat16 b; unsigned short u; } c;
  c.b = __float2bfloat16(v);
  return c.u;
}

// ---------------------------------------------------------------------------
// prep: detect dtypes, convert weights to fp32, build folded M, v, and the
// MFMA-ready bf16 tables W1T[feat][k] (k: 0..4=ew1 rows, 5=eb1, 6,7=0) and
// MT[feat][k] = bf16(M[k][feat]).
// ---------------------------------------------------------------------------
__global__ __launch_bounds__(256) void prep_kernel(
    const void* xv, const void* eiv, WPtrs wp, float* ws)
{
  __shared__ int red[2];
  __shared__ int s_ft;
  __shared__ float ew2s[4096];
  __shared__ float nw1s[4096];
  const int t = threadIdx.x;

  if (t == 0) { red[0] = 0; red[1] = 0; }
  __syncthreads();
  {
    const unsigned* u = (const unsigned*)xv;
    int big = 0;
    for (int i = t; i < 512; i += 256) {
      const unsigned el = (u[i] >> 7) & 0xFFu;
      big += (el >= 140u) ? 1 : 0;
    }
    atomicAdd(&red[0], big);
  }
  {
    const int* e32 = (const int*)eiv;
    int orv = 0;
    for (int i = 1 + 2 * t; i < 2048; i += 512) orv |= e32[i];
    atomicOr(&red[1], orv);
  }
  __syncthreads();
  if (t == 0) {
    const int ft = (red[0] < 8) ? 1 : 0;
    const int it = (red[1] == 0) ? 1 : 0;
    ((int*)(ws + OFF_FLAGS))[0] = ft;
    ((int*)(ws + OFF_FLAGS))[1] = it;
    s_ft = ft;
  }
  __syncthreads();
  const int ft = s_ft;

  const int sz[16]  = {320,64,4096,64,4160,64,4096,64,4096,64,4096,64,4096,64,128,2};
  const int dst[16] = {OFF_EW1,OFF_EB1,OFF_EW2,OFF_EB2,OFF_NW1,OFF_NB1,OFF_NW2,OFF_NB2,
                       OFF_OW1,OFF_OB1,OFF_OW2,OFF_OB2,OFF_OW3,OFF_OB3,OFF_OW4,OFF_OB4};
  for (int a = 0; a < 16; ++a) {
    const void* src = wp.p[a];
    float* d = ws + dst[a];
    const int n = sz[a];
    for (int i = t; i < n; i += 256)
      d[i] = ft ? __bfloat162float(((const __hip_bfloat16*)src)[i])
                : ((const float*)src)[i];
  }
  __syncthreads();

  for (int i = t; i < 4096; i += 256) {
    ew2s[i] = ws[OFF_EW2 + i];
    nw1s[i] = ws[OFF_NW1 + 64 + i];
  }
  __syncthreads();
  for (int idx = t; idx < 4096; idx += 256) {
    const int i = idx >> 6, j = idx & 63;
    float s = 0.0f;
    #pragma unroll 8
    for (int k = 0; k < 64; ++k)
      s = fmaf(ew2s[i * 64 + k], nw1s[k * 64 + j], s);
    ws[OFF_M + idx] = s;
  }
  for (int j = t; j < 64; j += 256) {
    float s = 0.0f;
    #pragma unroll 8
    for (int k = 0; k < 64; ++k)
      s = fmaf(ws[OFF_EB2 + k], nw1s[k * 64 + j], s);
    ws[OFF_V + j] = s;
  }
  __syncthreads();

  // W1T: [n][k] k<5 -> ew1[k][n], k==5 -> eb1[n], else 0
  unsigned short* w1t = (unsigned short*)(ws + OFF_W1T);
  for (int n = t; n < 64; n += 256) {
    #pragma unroll
    for (int k = 0; k < 8; ++k) {
      float v = 0.0f;
      if (k < 5) v = ws[OFF_EW1 + k * 64 + n];
      else if (k == 5) v = ws[OFF_EB1 + n];
      w1t[n * 8 + k] = f2bu(v);
    }
  }
  // MT: [n][k] = bf16(M[k][n])
  unsigned short* mt = (unsigned short*)(ws + OFF_MT);
  for (int idx = t; idx < 4096; idx += 256) {
    const int n = idx >> 6, k = idx & 63;
    mt[idx] = f2bu(ws[OFF_M + k * 64 + n]);
  }
}

// ---------------------------------------------------------------------------
// count: per-block LDS histogram; gcnt[bucket*NCB + block] (bucket-major).
// ---------------------------------------------------------------------------
template<typename IT>
__device__ __forceinline__ void count_impl(
    const IT* __restrict__ ei, int* __restrict__ gcnt, int* lh,
    const int E, const int NB)
{
  const int t = threadIdx.x;
  const int b = blockIdx.x;
  for (int i = t; i < NB; i += 256) lh[i] = 0;
  __syncthreads();
  const int per = (E + NCB - 1) / NCB;
  const int a = b * per;
  const int bnd = (a + per < E) ? (a + per) : E;
  for (int e = a + t; e < bnd; e += 256) {
    const int c = (int)ei[(size_t)E + e];
    atomicAdd(&lh[c >> 5], 1);
  }
  __syncthreads();
  for (int i = t; i < NB; i += 256) gcnt[(size_t)i * NCB + b] = lh[i];
}

__global__ __launch_bounds__(256) void count_kernel(
    const void* eiv, const float* ws, int* gcnt, const int E, const int NB)
{
  __shared__ int lh[MAXNB];
  const int it = ((const int*)(ws + OFF_FLAGS))[1];
  if (it) count_impl<long long>((const long long*)eiv, gcnt, lh, E, NB);
  else    count_impl<int>((const int*)eiv, gcnt, lh, E, NB);
}

// ---------------------------------------------------------------------------
// scan, parallelized (r9: single-block scan was the 167 us top dispatch):
//  scan_tot : one wave per bucket -> bucket total into bstart[bkt]
//  scan_pref: 1 block, exclusive prefix over NB totals (in place) + total
//  scan_row : one wave per bucket -> exclusive scan of its 256 partials + base
// ---------------------------------------------------------------------------
__global__ __launch_bounds__(256) void scan_tot_kernel(
    const int* __restrict__ gcnt, int* __restrict__ bstart, const int NB)
{
  const int lane = threadIdx.x & 63;
  const int bkt = blockIdx.x * 4 + (threadIdx.x >> 6);
  if (bkt >= NB) return;
  const int4 v = *(const int4*)(gcnt + (size_t)bkt * NCB + lane * 4);
  int s = v.x + v.y + v.z + v.w;
  #pragma unroll
  for (int off = 32; off > 0; off >>= 1) s += __shfl_xor(s, off);
  if (lane == 0) bstart[bkt] = s;
}

__global__ __launch_bounds__(256) void scan_pref_kernel(
    int* __restrict__ bstart, const int NB)
{
  __shared__ int ps[256];
  const int t = threadIdx.x;
  const int seg = (NB + 255) / 256;
  int s = 0;
  for (int i = 0; i < seg; ++i) {
    const int idx = t * seg + i;
    if (idx < NB) s += bstart[idx];
  }
  ps[t] = s;
  __syncthreads();
  for (int off = 1; off < 256; off <<= 1) {
    const int v = (t >= off) ? ps[t - off] : 0;
    __syncthreads();
    ps[t] += v;
    __syncthreads();
  }
  int carry = ps[t] - s;   // exclusive prefix of this thread's segment
  for (int i = 0; i < seg; ++i) {
    const int idx = t * seg + i;
    if (idx < NB) {
      const int c = bstart[idx];
      bstart[idx] = carry;
      carry += c;
    }
  }
  if (t == 255) bstart[NB] = ps[255];
}

__global__ __launch_bounds__(256) void scan_row_kernel(
    int* __restrict__ gcnt, const int* __restrict__ bstart, const int NB)
{
  const int lane = threadIdx.x & 63;
  const int bkt = blockIdx.x * 4 + (threadIdx.x >> 6);
  if (bkt >= NB) return;
  int* row = gcnt + (size_t)bkt * NCB;
  const int4 v = *(const int4*)(row + lane * 4);
  const int ls = v.x + v.y + v.z + v.w;
  int s = ls;
  #pragma unroll
  for (int off = 1; off < 64; off <<= 1) {
    const int u = __shfl_up(s, off);
    if (lane >= off) s += u;
  }
  int e = s - ls + bstart[bkt];   // exclusive prefix for this lane's 4 elems
  int4 o;
  o.x = e; e += v.x;
  o.y = e; e += v.y;
  o.z = e; e += v.z;
  o.w = e;
  *(int4*)(row + lane * 4) = o;
}

// ---------------------------------------------------------------------------
// scatter (per group): write sorted bf16 payload recB[pos]={xr,a0,a1,a2} +
// cid[pos]=col&31 for buckets [gb0,gb1). LDS cursors; zero global atomics.
// ---------------------------------------------------------------------------
template<typename FT, typename IT>
__device__ __forceinline__ void scatter_impl(
    const FT* __restrict__ x, const IT* __restrict__ ei, const FT* __restrict__ ea,
    const int* __restrict__ gcnt, const int* __restrict__ bstart,
    ushort4* __restrict__ recB, unsigned char* __restrict__ cid, int* lb,
    const int E, const int NB, const int gb0, const int gb1, const int cap)
{
  const int t = threadIdx.x;
  const int b = blockIdx.x;
  __shared__ int sbase;
  if (t == 0) sbase = bstart[gb0];
  __syncthreads();
  const int base = sbase;
  const int gcount = gb1 - gb0;
  for (int i = t; i < gcount; i += 256) lb[i] = gcnt[(size_t)(gb0 + i) * NCB + b] - base;
  __syncthreads();

  const int per = (E + NCB - 1) / NCB;
  const int a = b * per;
  const int bnd = (a + per < E) ? (a + per) : E;
  for (int e = a + t; e < bnd; e += 256) {
    const int c = (int)ei[(size_t)E + e];
    const int bkt = c >> 5;
    if (bkt >= gb0 && bkt < gb1) {
      const int pos = atomicAdd(&lb[bkt - gb0], 1);
      if (pos < cap) {
        const int r = (int)ei[e];
        ushort4 rv;
        rv.x = f2bu(cv(x[r]));
        rv.y = f2bu(cv(ea[(size_t)3 * e + 0]));
        rv.z = f2bu(cv(ea[(size_t)3 * e + 1]));
        rv.w = f2bu(cv(ea[(size_t)3 * e + 2]));
        recB[pos] = rv;
        cid[pos] = (unsigned char)(c & 31);
      }
    }
  }
}

__global__ __launch_bounds__(256) void scatter_kernel(
    const void* xv, const void* eiv, const void* eav, const float* ws,
    const int* gcnt, const int* bstart, ushort4* recB, unsigned char* cid,
    const int E, const int NB, const int gb0, const int gb1, const int cap)
{
  __shared__ int lb[MAXNB];
  const int* fl = (const int*)(ws + OFF_FLAGS);
  const int ft = fl[0], it = fl[1];
  if (ft) {
    if (it) scatter_impl<__hip_bfloat16, long long>((const __hip_bfloat16*)xv, (const long long*)eiv, (const __hip_bfloat16*)eav, gcnt, bstart, recB, cid, lb, E, NB, gb0, gb1, cap);
    else    scatter_impl<__hip_bfloat16, int>((const __hip_bfloat16*)xv, (const int*)eiv, (const __hip_bfloat16*)eav, gcnt, bstart, recB, cid, lb, E, NB, gb0, gb1, cap);
  } else {
    if (it) scatter_impl<float, long long>((const float*)xv, (const long long*)eiv, (const float*)eav, gcnt, bstart, recB, cid, lb, E, NB, gb0, gb1, cap);
    else    scatter_impl<float, int>((const float*)xv, (const int*)eiv, (const float*)eav, gcnt, bstart, recB, cid, lb, E, NB, gb0, gb1, cap);
  }
}

// ---------------------------------------------------------------------------
// fused (MFMA): block owns bucket gb0+blockIdx.x (32 nodes, ~1024 edges).
// GEMM1: H = relu(A[64x32] @ W1); GEMM2: agg += S @ H, deg += S @ 1;
// node GEMM: agg @ M; epilogue + pooled accumulation.
// ---------------------------------------------------------------------------
template<typename FT, typename IT>
__device__ __forceinline__ void fused_impl(
    const FT* __restrict__ x, const IT* __restrict__ batch,
    const float* __restrict__ ws, const int* __restrict__ bstart,
    const ushort4* __restrict__ recB, const unsigned char* __restrict__ cid,
    float* __restrict__ rep,
    short* sA, unsigned char* scid, short* sHT, float* aggF,
    float* pooledL, float* xls, int* sbi,
    const int N, const int gb0, const int cap)
{
  const int t = threadIdx.x;
  const int lane = t & 63;
  const int quad = lane >> 4;
  const int l15 = lane & 15;
  const int wav = t >> 6;
  const int bucket = gb0 + blockIdx.x;

  for (int i = t; i < 32 * 68; i += 256) aggF[i] = 0.0f;
  for (int i = t; i < NGRAPH * 64; i += 256) pooledL[i] = 0.0f;
  if (t < BN) {
    const int n = bucket * BN + t;
    xls[t] = (n < N) ? cv(x[n]) : 0.0f;
  }
  if (t == 0) {
    const int nf = bucket * BN, nl = bucket * BN + BN - 1;
    sbi[0] = (int)batch[(nf < N) ? nf : (N - 1)];
    sbi[1] = (int)batch[(nl < N) ? nl : (N - 1)];
    sbi[2] = bstart[gb0];
  }
  __syncthreads();

  const unsigned short* w1t = (const unsigned short*)(ws + OFF_W1T);
  short8 B1[4];
  #pragma unroll
  for (int tn = 0; tn < 4; ++tn) {
    short8 z; for (int j = 0; j < 8; ++j) z[j] = 0;
    if (quad == 0) z = *(const short8*)(w1t + (16 * tn + l15) * 8);
    B1[tn] = z;
  }
  short8 ONES8;
  #pragma unroll
  for (int j = 0; j < 8; ++j) ONES8[j] = (short)0x3F80;

  const int base = sbi[2];
  int s0 = bstart[bucket] - base;
  int e0 = bstart[bucket + 1] - base;
  if (s0 > cap) s0 = cap;
  if (e0 > cap) e0 = cap;

  f32x4 C2[2][4];
  f32x4 C3[2];
  #pragma unroll
  for (int i = 0; i < 2; ++i) {
    #pragma unroll
    for (int j2 = 0; j2 < 4; ++j2) { C2[i][j2] = (f32x4)0.0f; }
    C3[i] = (f32x4)0.0f;
  }

  short* mysA = sA + wav * 64 * 8;
  unsigned char* myscid = scid + wav * 64;
  short* mysHT = sHT + wav * 64 * 72;

  const int ntile = (e0 - s0 + 63) >> 6;
  for (int tt = wav; tt < ntile; tt += 4) {
    const int eb = s0 + tt * 64;
    const int idx = eb + lane;
    const bool valid = idx < e0;
    ushort4 rv = valid ? recB[idx] : make_ushort4(0, 0, 0, 0);
    const int c = valid ? (int)cid[idx] : 255;
    const unsigned short xcb = valid ? f2bu(xls[c]) : (unsigned short)0;

    short8 row;
    row[0] = (short)rv.x; row[1] = (short)xcb;
    row[2] = (short)rv.y; row[3] = (short)rv.z; row[4] = (short)rv.w;
    row[5] = valid ? (short)0x3F80 : (short)0;
    row[6] = 0; row[7] = 0;
    *(short8*)(mysA + lane * 8) = row;
    myscid[lane] = (unsigned char)c;

    f32x4 Hc[4][4];
    #pragma unroll
    for (int tm = 0; tm < 4; ++tm) {
      short8 a1;
      if (quad == 0) a1 = *(const short8*)(mysA + (16 * tm + l15) * 8);
      else { for (int j = 0; j < 8; ++j) a1[j] = 0; }
      #pragma unroll
      for (int tn = 0; tn < 4; ++tn)
        Hc[tm][tn] = __builtin_amdgcn_mfma_f32_16x16x32_bf16(a1, B1[tn], (f32x4)0.0f, 0, 0, 0);
    }
    #pragma unroll
    for (int tm = 0; tm < 4; ++tm) {
      #pragma unroll
      for (int tn = 0; tn < 4; ++tn) {
        unsigned short u0 = f2bu(fmaxf(Hc[tm][tn][0], 0.0f));
        unsigned short u1 = f2bu(fmaxf(Hc[tm][tn][1], 0.0f));
        unsigned short u2 = f2bu(fmaxf(Hc[tm][tn][2], 0.0f));
        unsigned short u3 = f2bu(fmaxf(Hc[tm][tn][3], 0.0f));
        uint2 pk;
        pk.x = (unsigned)u0 | ((unsigned)u1 << 16);
        pk.y = (unsigned)u2 | ((unsigned)u3 << 16);
        *(uint2*)(mysHT + (16 * tn + l15) * 72 + 16 * tm + quad * 4) = pk;
      }
    }
    const unsigned* sp = (const unsigned*)myscid;
    #pragma unroll
    for (int q = 0; q < 2; ++q) {
      const unsigned lo = sp[2 * quad + 8 * q];
      const unsigned hi = sp[2 * quad + 8 * q + 1];
      short8 a2[2];
      #pragma unroll
      for (int tm2 = 0; tm2 < 2; ++tm2) {
        const int seg = 16 * tm2 + l15;
        short8 v;
        v[0] = (((lo      ) & 255u) == (unsigned)seg) ? (short)0x3F80 : (short)0;
        v[1] = (((lo >>  8) & 255u) == (unsigned)seg) ? (short)0x3F80 : (short)0;
        v[2] = (((lo >> 16) & 255u) == (unsigned)seg) ? (short)0x3F80 : (short)0;
        v[3] = (((lo >> 24) & 255u) == (unsigned)seg) ? (short)0x3F80 : (short)0;
        v[4] = (((hi      ) & 255u) == (unsigned)seg) ? (short)0x3F80 : (short)0;
        v[5] = (((hi >>  8) & 255u) == (unsigned)seg) ? (short)0x3F80 : (short)0;
        v[6] = (((hi >> 16) & 255u) == (unsigned)seg) ? (short)0x3F80 : (short)0;
        v[7] = (((hi >> 24) & 255u) == (unsigned)seg) ? (short)0x3F80 : (short)0;
        a2[tm2] = v;
      }
      #pragma unroll
      for (int tn2 = 0; tn2 < 4; ++tn2) {
        const short8 b2 = *(const short8*)(mysHT + (16 * tn2 + l15) * 72 + 32 * q + quad * 8);
        #pragma unroll
        for (int tm2 = 0; tm2 < 2; ++tm2)
          C2[tm2][tn2] = __builtin_amdgcn_mfma_f32_16x16x32_bf16(a2[tm2], b2, C2[tm2][tn2], 0, 0, 0);
      }
      #pragma unroll
      for (int tm2 = 0; tm2 < 2; ++tm2)
        C3[tm2] = __builtin_amdgcn_mfma_f32_16x16x32_bf16(a2[tm2], ONES8, C3[tm2], 0, 0, 0);
    }
  }

  __syncthreads();
  #pragma unroll
  for (int tm2 = 0; tm2 < 2; ++tm2) {
    #pragma unroll
    for (int tn2 = 0; tn2 < 4; ++tn2) {
      #pragma unroll
      for (int r = 0; r < 4; ++r)
        atomicAdd(&aggF[(16 * tm2 + quad * 4 + r) * 68 + 16 * tn2 + l15], C2[tm2][tn2][r]);
    }
    if (l15 == 0) {
      #pragma unroll
      for (int r = 0; r < 4; ++r)
        atomicAdd(&aggF[(16 * tm2 + quad * 4 + r) * 68 + 64], C3[tm2][r]);
    }
  }
  __syncthreads();

  const unsigned short* mt = (const unsigned short*)(ws + OFF_MT);
  f32x4 D[2];
  D[0] = (f32x4)0.0f; D[1] = (f32x4)0.0f;
  #pragma unroll
  for (int q = 0; q < 2; ++q) {
    const short8 bb = *(const short8*)(mt + (16 * wav + l15) * 64 + 32 * q + quad * 8);
    #pragma unroll
    for (int tm2 = 0; tm2 < 2; ++tm2) {
      const float4 p0 = *(const float4*)(&aggF[(16 * tm2 + l15) * 68 + quad * 8 + 32 * q]);
      const float4 p1 = *(const float4*)(&aggF[(16 * tm2 + l15) * 68 + quad * 8 + 32 * q + 4]);
      short8 aa;
      aa[0] = (short)f2bu(p0.x); aa[1] = (short)f2bu(p0.y);
      aa[2] = (short)f2bu(p0.z); aa[3] = (short)f2bu(p0.w);
      aa[4] = (short)f2bu(p1.x); aa[5] = (short)f2bu(p1.y);
      aa[6] = (short)f2bu(p1.z); aa[7] = (short)f2bu(p1.w);
      D[tm2] = __builtin_amdgcn_mfma_f32_16x16x32_bf16(aa, bb, D[tm2], 0, 0, 0);
    }
  }

  const int n = 16 * wav + l15;
  const float c1n = ws[OFF_NW1 + n];
  const float vn  = ws[OFF_V + n];
  const float bn  = ws[OFF_NB1 + n];
  #pragma unroll
  for (int tm2 = 0; tm2 < 2; ++tm2) {
    #pragma unroll
    for (int r = 0; r < 4; ++r) {
      const int m = 16 * tm2 + quad * 4 + r;
      const int ng = bucket * BN + m;
      if (ng < N) {
        const float deg = aggF[m * 68 + 64];
        const float h = fmaxf(D[tm2][r] + xls[m] * c1n + deg * vn + bn, 0.0f);
        const int g = (int)batch[ng];
        atomicAdd(&pooledL[g * 64 + n], h);
      }
    }
  }
  __syncthreads();

  float* myrep = rep + (size_t)(bucket & 7) * (NGRAPH * 64);
  for (int g = sbi[0] + wav; g <= sbi[1]; g += 4)
    unsafeAtomicAdd(&myrep[g * 64 + lane], pooledL[g * 64 + lane]);
}

__global__ __launch_bounds__(256) void fused_kernel(
    const void* xv, const void* batv, const float* ws, const int* bstart,
    const ushort4* recB, const unsigned char* cid, float* rep,
    const int N, const int gb0, const int cap)
{
  __shared__ __align__(16) short sA[4 * 64 * 8];
  __shared__ __align__(8)  unsigned char scid[4 * 64];
  __shared__ __align__(16) short sHT[4 * 64 * 72];
  __shared__ __align__(16) float aggF[32 * 68];
  __shared__ float pooledL[NGRAPH * 64];
  __shared__ float xls[BN];
  __shared__ int   sbi[3];

  const int* fl = (const int*)(ws + OFF_FLAGS);
  const int ft = fl[0], it = fl[1];
  if (ft) {
    if (it) fused_impl<__hip_bfloat16, long long>((const __hip_bfloat16*)xv, (const long long*)batv, ws, bstart, recB, cid, rep, sA, scid, sHT, aggF, pooledL, xls, sbi, N, gb0, cap);
    else    fused_impl<__hip_bfloat16, int>((const __hip_bfloat16*)xv, (const int*)batv, ws, bstart, recB, cid, rep, sA, scid, sHT, aggF, pooledL, xls, sbi, N, gb0, cap);
  } else {
    if (it) fused_impl<float, long long>((const float*)xv, (const long long*)batv, ws, bstart, recB, cid, rep, sA, scid, sHT, aggF, pooledL, xls, sbi, N, gb0, cap);
    else    fused_impl<float, int>((const float*)xv, (const int*)batv, ws, bstart, recB, cid, rep, sA, scid, sHT, aggF, pooledL, xls, sbi, N, gb0, cap);
  }
}

// ---------------------------------------------------------------------------
// head: reduce 8 pooled replicas; cnt via sorted-boundary detection (unique
// plain LDS writes, no same-address atomics); then dense head.
// ---------------------------------------------------------------------------
__global__ __launch_bounds__(256) void head_kernel(
    const float* ws, const float* rep, const void* batv, void* outv, const int N)
{
  __shared__ float P[NGRAPH][HID];
  __shared__ float A[NGRAPH][HID];
  __shared__ float B[NGRAPH][HID];
  __shared__ int endL[NGRAPH];

  const int t = threadIdx.x;
  const int j = t & 63;
  const int gq = t >> 6;

  const int it = ((const int*)(ws + OFF_FLAGS))[1];
  if (it) {
    const long long* bt = (const long long*)batv;
    for (int i = t; i < N; i += 256) {
      const int g1 = (int)bt[i];
      if (i == 0) for (int g = 0; g < g1; ++g) endL[g] = 0;
      if (i == N - 1) { for (int g = g1; g < NGRAPH; ++g) endL[g] = N; }
      else {
        const int g2 = (int)bt[i + 1];
        for (int g = g1; g < g2; ++g) endL[g] = i + 1;
      }
    }
  } else {
    const int* bt = (const int*)batv;
    for (int i = t; i < N; i += 256) {
      const int g1 = bt[i];
      if (i == 0) for (int g = 0; g < g1; ++g) endL[g] = 0;
      if (i == N - 1) { for (int g = g1; g < NGRAPH; ++g) endL[g] = N; }
      else {
        const int g2 = bt[i + 1];
        for (int g = g1; g < g2; ++g) endL[g] = i + 1;
      }
    }
  }

  #pragma unroll
  for (int gi = 0; gi < 4; ++gi) {
    const int g = gq + gi * 4;
    float s = 0.0f;
    #pragma unroll
    for (int r = 0; r < 8; ++r)
      s += rep[(size_t)r * (NGRAPH * 64) + g * 64 + j];
    P[g][j] = s;
  }
  __syncthreads();

  {
    const float bj = ws[OFF_NB2 + j];
    #pragma unroll
    for (int gi = 0; gi < 4; ++gi) {
      const int g = gq + gi * 4;
      const float cg = (float)(endL[g] - (g ? endL[g - 1] : 0));
      float s = cg * bj;
      #pragma unroll 8
      for (int k = 0; k < HID; ++k)
        s = fmaf(P[g][k], ws[OFF_NW2 + k * HID + j], s);
      A[g][j] = s;
    }
  }
  __syncthreads();

  const int wOff[3] = {OFF_OW1, OFF_OW2, OFF_OW3};
  const int bOff[3] = {OFF_OB1, OFF_OB2, OFF_OB3};
  for (int L = 0; L < 3; ++L) {
    float (*In)[HID]  = (L & 1) ? B : A;
    float (*Out)[HID] = (L & 1) ? A : B;
    const float bj = ws[bOff[L] + j];
    #pragma unroll
    for (int gi = 0; gi < 4; ++gi) {
      const int g = gq + gi * 4;
      float s = bj;
      #pragma unroll 8
      for (int k = 0; k < HID; ++k)
        s = fmaf(In[g][k], ws[wOff[L] + k * HID + j], s);
      Out[g][j] = fmaxf(s, 0.0f);
    }
    __syncthreads();
  }

  if (t < 32) {
    const int g = t >> 1, d = t & 1;
    float s = ws[OFF_OB4 + d];
    #pragma unroll 8
    for (int k = 0; k < HID; ++k)
      s = fmaf(B[g][k], ws[OFF_OW4 + k * 2 + d], s);
    const int ft = ((const int*)(ws + OFF_FLAGS))[0];
    if (ft) ((__hip_bfloat16*)outv)[g * 2 + d] = __float2bfloat16(s);
    else    ((float*)outv)[g * 2 + d] = s;
  }
}

extern "C" void kernel_launch(void* const* d_in, const int* in_sizes, int n_in,
                              void* d_out, int out_size, void* d_ws, size_t ws_size,
                              hipStream_t stream)
{
  const void* xv   = d_in[0];
  const void* eiv  = d_in[1];
  const void* eav  = d_in[2];
  const void* batv = d_in[3];

  WPtrs wp;
  for (int a = 0; a < 16; ++a) wp.p[a] = d_in[4 + a];

  const int N = in_sizes[0];
  const int E = in_sizes[1] / 2;
  const int NB = (N + BN - 1) / BN;
  if (NB > MAXNB) return;

  float* ws   = (float*)d_ws;
  float* rep  = ws + OFF_PREP;                             // 8*1024 floats
  int* bstart = (int*)(rep + 8 * NGRAPH * 64);             // NB+1 ints
  int* gcnt   = bstart + NB + 1;                           // NB*NCB ints

  size_t recOffB = ((size_t)((char*)(gcnt + (size_t)NB * NCB) - (char*)d_ws) + 15) & ~(size_t)15;

  int G = -1; long long cap = 0;
  for (int g = 1; g <= 64; ++g) {
    const long long c = (long long)E / g + E / 32 + 8192;
    if (recOffB + (size_t)c * 9 <= ws_size) { G = g; cap = c; break; }
  }
  if (G < 0) return;

  ushort4* recB = (ushort4*)((char*)d_ws + recOffB);
  unsigned char* cid = (unsigned char*)(recB + cap);
  const int gsz = (NB + G - 1) / G;
  const int sblk = (NB + 3) / 4;

  hipMemsetAsync(rep, 0, (size_t)(8 * NGRAPH * 64) * 4, stream);

  prep_kernel<<<1, 256, 0, stream>>>(xv, eiv, wp, ws);
  count_kernel<<<NCB, 256, 0, stream>>>(eiv, ws, gcnt, E, NB);
  scan_tot_kernel<<<sblk, 256, 0, stream>>>(gcnt, bstart, NB);
  scan_pref_kernel<<<1, 256, 0, stream>>>(bstart, NB);
  scan_row_kernel<<<sblk, 256, 0, stream>>>(gcnt, bstart, NB);

  for (int g = 0; g < G; ++g) {
    const int gb0 = g * gsz;
    const int gb1 = (gb0 + gsz < NB) ? (gb0 + gsz) : NB;
    if (gb0 >= gb1) break;
    scatter_kernel<<<NCB, 256, 0, stream>>>(xv, eiv, eav, ws, gcnt, bstart,
                                            recB, cid, E, NB, gb0, gb1, (int)cap);
    fused_kernel<<<gb1 - gb0, 256, 0, stream>>>(xv, batv, ws, bstart, recB, cid,
                                                rep, N, gb0, (int)cap);
  }

  head_kernel<<<1, 256, 0, stream>>>(ws, rep, batv, d_out, N);
}

// Round 11
// 395.733 us; speedup vs baseline: 2.8692x; 1.1777x over previous
//
#include <hip/hip_runtime.h>
#include <hip/hip_bf16.h>

#define HID 64
#define NGRAPH 16
#define BN 32            // nodes per bucket
#define MAXNB 2048
#define NCB 256          // count/scatter blocks

typedef __attribute__((ext_vector_type(8))) short short8;
typedef __attribute__((ext_vector_type(4))) float f32x4;

// Fixed workspace layout (float offsets)
enum : int {
  OFF_V      = 1040,
  OFF_M      = 1104,
  OFF_EW1    = 5200,
  OFF_EB1    = 5520,
  OFF_NW1    = 5584,
  OFF_NB1    = 9744,
  OFF_NW2    = 9808,
  OFF_NB2    = 13904,
  OFF_OW1    = 13968,
  OFF_OB1    = 18064,
  OFF_OW2    = 18128,
  OFF_OB2    = 22224,
  OFF_OW3    = 22288,
  OFF_OB3    = 26384,
  OFF_OW4    = 26448,
  OFF_OB4    = 26576,
  OFF_EW2    = 26578,
  OFF_EB2    = 30674,
  OFF_FLAGS  = 30738,                 // 2 ints: [0]=ft (1=bf16), [1]=it (1=int64)
  OFF_W1T    = 30740,                 // 512 shorts (64 feats x 8 k)
  OFF_MT     = 30996,                 // 4096 shorts (M^T bf16)
  OFF_PREP   = 33044                  // rep: 8 pooled replicas * 16*64
};

struct WPtrs { const void* p[16]; };

__device__ __forceinline__ float cv(float v) { return v; }
__device__ __forceinline__ float cv(__hip_bfloat16 v) { return __bfloat162float(v); }
__device__ __forceinline__ unsigned short f2bu(float v) {   // cold path only
  union { __hip_bfloat16 b; unsigned short u; } c;
  c.b = __float2bfloat16(v);
  return c.u;
}
// fast RNE f32->bf16 (finite inputs): 3 VALU inst
__device__ __forceinline__ unsigned short fr(float v) {
  unsigned u = __float_as_uint(v);
  u += 0x7FFFu + ((u >> 16) & 1u);
  return (unsigned short)(u >> 16);
}
// relu + RNE-round two floats, pack into one dword (lo = a, hi = b)
__device__ __forceinline__ unsigned rndpack(float a, float b) {
  unsigned ua = __float_as_uint(fmaxf(a, 0.0f));
  unsigned ub = __float_as_uint(fmaxf(b, 0.0f));
  ua += 0x7FFFu + ((ua >> 16) & 1u);
  ub += 0x7FFFu + ((ub >> 16) & 1u);
  return __builtin_amdgcn_perm(ub, ua, 0x07060302u);
}

// ---------------------------------------------------------------------------
// prep: detect dtypes, convert weights to fp32, build folded M, v, W1T, MT.
// ---------------------------------------------------------------------------
__global__ __launch_bounds__(256) void prep_kernel(
    const void* xv, const void* eiv, WPtrs wp, float* ws)
{
  __shared__ int red[2];
  __shared__ int s_ft;
  __shared__ float ew2s[4096];
  __shared__ float nw1s[4096];
  const int t = threadIdx.x;

  if (t == 0) { red[0] = 0; red[1] = 0; }
  __syncthreads();
  {
    const unsigned* u = (const unsigned*)xv;
    int big = 0;
    for (int i = t; i < 512; i += 256) {
      const unsigned el = (u[i] >> 7) & 0xFFu;
      big += (el >= 140u) ? 1 : 0;
    }
    atomicAdd(&red[0], big);
  }
  {
    const int* e32 = (const int*)eiv;
    int orv = 0;
    for (int i = 1 + 2 * t; i < 2048; i += 512) orv |= e32[i];
    atomicOr(&red[1], orv);
  }
  __syncthreads();
  if (t == 0) {
    const int ft = (red[0] < 8) ? 1 : 0;
    const int it = (red[1] == 0) ? 1 : 0;
    ((int*)(ws + OFF_FLAGS))[0] = ft;
    ((int*)(ws + OFF_FLAGS))[1] = it;
    s_ft = ft;
  }
  __syncthreads();
  const int ft = s_ft;

  const int sz[16]  = {320,64,4096,64,4160,64,4096,64,4096,64,4096,64,4096,64,128,2};
  const int dst[16] = {OFF_EW1,OFF_EB1,OFF_EW2,OFF_EB2,OFF_NW1,OFF_NB1,OFF_NW2,OFF_NB2,
                       OFF_OW1,OFF_OB1,OFF_OW2,OFF_OB2,OFF_OW3,OFF_OB3,OFF_OW4,OFF_OB4};
  for (int a = 0; a < 16; ++a) {
    const void* src = wp.p[a];
    float* d = ws + dst[a];
    const int n = sz[a];
    for (int i = t; i < n; i += 256)
      d[i] = ft ? __bfloat162float(((const __hip_bfloat16*)src)[i])
                : ((const float*)src)[i];
  }
  __syncthreads();

  for (int i = t; i < 4096; i += 256) {
    ew2s[i] = ws[OFF_EW2 + i];
    nw1s[i] = ws[OFF_NW1 + 64 + i];
  }
  __syncthreads();
  for (int idx = t; idx < 4096; idx += 256) {
    const int i = idx >> 6, j = idx & 63;
    float s = 0.0f;
    #pragma unroll 8
    for (int k = 0; k < 64; ++k)
      s = fmaf(ew2s[i * 64 + k], nw1s[k * 64 + j], s);
    ws[OFF_M + idx] = s;
  }
  for (int j = t; j < 64; j += 256) {
    float s = 0.0f;
    #pragma unroll 8
    for (int k = 0; k < 64; ++k)
      s = fmaf(ws[OFF_EB2 + k], nw1s[k * 64 + j], s);
    ws[OFF_V + j] = s;
  }
  __syncthreads();

  unsigned short* w1t = (unsigned short*)(ws + OFF_W1T);
  for (int n = t; n < 64; n += 256) {
    #pragma unroll
    for (int k = 0; k < 8; ++k) {
      float v = 0.0f;
      if (k < 5) v = ws[OFF_EW1 + k * 64 + n];
      else if (k == 5) v = ws[OFF_EB1 + n];
      w1t[n * 8 + k] = f2bu(v);
    }
  }
  unsigned short* mt = (unsigned short*)(ws + OFF_MT);
  for (int idx = t; idx < 4096; idx += 256) {
    const int n = idx >> 6, k = idx & 63;
    mt[idx] = f2bu(ws[OFF_M + k * 64 + n]);
  }
}

// ---------------------------------------------------------------------------
// count: per-block LDS histogram; gcnt[bucket*NCB + block] (bucket-major).
// ---------------------------------------------------------------------------
template<typename IT>
__device__ __forceinline__ void count_impl(
    const IT* __restrict__ ei, int* __restrict__ gcnt, int* lh,
    const int E, const int NB)
{
  const int t = threadIdx.x;
  const int b = blockIdx.x;
  for (int i = t; i < NB; i += 256) lh[i] = 0;
  __syncthreads();
  const int per = (E + NCB - 1) / NCB;
  const int a = b * per;
  const int bnd = (a + per < E) ? (a + per) : E;
  for (int e = a + t; e < bnd; e += 256) {
    const int c = (int)ei[(size_t)E + e];
    atomicAdd(&lh[c >> 5], 1);
  }
  __syncthreads();
  for (int i = t; i < NB; i += 256) gcnt[(size_t)i * NCB + b] = lh[i];
}

__global__ __launch_bounds__(256) void count_kernel(
    const void* eiv, const float* ws, int* gcnt, const int E, const int NB)
{
  __shared__ int lh[MAXNB];
  const int it = ((const int*)(ws + OFF_FLAGS))[1];
  if (it) count_impl<long long>((const long long*)eiv, gcnt, lh, E, NB);
  else    count_impl<int>((const int*)eiv, gcnt, lh, E, NB);
}

// ---------------------------------------------------------------------------
// scan (3-kernel parallel version, r10-verified)
// ---------------------------------------------------------------------------
__global__ __launch_bounds__(256) void scan_tot_kernel(
    const int* __restrict__ gcnt, int* __restrict__ bstart, const int NB)
{
  const int lane = threadIdx.x & 63;
  const int bkt = blockIdx.x * 4 + (threadIdx.x >> 6);
  if (bkt >= NB) return;
  const int4 v = *(const int4*)(gcnt + (size_t)bkt * NCB + lane * 4);
  int s = v.x + v.y + v.z + v.w;
  #pragma unroll
  for (int off = 32; off > 0; off >>= 1) s += __shfl_xor(s, off);
  if (lane == 0) bstart[bkt] = s;
}

__global__ __launch_bounds__(256) void scan_pref_kernel(
    int* __restrict__ bstart, const int NB)
{
  __shared__ int ps[256];
  const int t = threadIdx.x;
  const int seg = (NB + 255) / 256;
  int s = 0;
  for (int i = 0; i < seg; ++i) {
    const int idx = t * seg + i;
    if (idx < NB) s += bstart[idx];
  }
  ps[t] = s;
  __syncthreads();
  for (int off = 1; off < 256; off <<= 1) {
    const int v = (t >= off) ? ps[t - off] : 0;
    __syncthreads();
    ps[t] += v;
    __syncthreads();
  }
  int carry = ps[t] - s;
  for (int i = 0; i < seg; ++i) {
    const int idx = t * seg + i;
    if (idx < NB) {
      const int c = bstart[idx];
      bstart[idx] = carry;
      carry += c;
    }
  }
  if (t == 255) bstart[NB] = ps[255];
}

__global__ __launch_bounds__(256) void scan_row_kernel(
    int* __restrict__ gcnt, const int* __restrict__ bstart, const int NB)
{
  const int lane = threadIdx.x & 63;
  const int bkt = blockIdx.x * 4 + (threadIdx.x >> 6);
  if (bkt >= NB) return;
  int* row = gcnt + (size_t)bkt * NCB;
  const int4 v = *(const int4*)(row + lane * 4);
  const int ls = v.x + v.y + v.z + v.w;
  int s = ls;
  #pragma unroll
  for (int off = 1; off < 64; off <<= 1) {
    const int u = __shfl_up(s, off);
    if (lane >= off) s += u;
  }
  int e = s - ls + bstart[bkt];
  int4 o;
  o.x = e; e += v.x;
  o.y = e; e += v.y;
  o.z = e; e += v.z;
  o.w = e;
  *(int4*)(row + lane * 4) = o;
}

// ---------------------------------------------------------------------------
// scatter (per group): write sorted bf16 payload recB[pos]={xr,a0,a1,a2} +
// cid[pos]=col&31 for buckets [gb0,gb1). LDS cursors; zero global atomics.
// ---------------------------------------------------------------------------
template<typename FT, typename IT>
__device__ __forceinline__ void scatter_impl(
    const FT* __restrict__ x, const IT* __restrict__ ei, const FT* __restrict__ ea,
    const int* __restrict__ gcnt, const int* __restrict__ bstart,
    ushort4* __restrict__ recB, unsigned char* __restrict__ cid, int* lb,
    const int E, const int NB, const int gb0, const int gb1, const int cap)
{
  const int t = threadIdx.x;
  const int b = blockIdx.x;
  __shared__ int sbase;
  if (t == 0) sbase = bstart[gb0];
  __syncthreads();
  const int base = sbase;
  const int gcount = gb1 - gb0;
  for (int i = t; i < gcount; i += 256) lb[i] = gcnt[(size_t)(gb0 + i) * NCB + b] - base;
  __syncthreads();

  const int per = (E + NCB - 1) / NCB;
  const int a = b * per;
  const int bnd = (a + per < E) ? (a + per) : E;
  for (int e = a + t; e < bnd; e += 256) {
    const int c = (int)ei[(size_t)E + e];
    const int bkt = c >> 5;
    if (bkt >= gb0 && bkt < gb1) {
      const int pos = atomicAdd(&lb[bkt - gb0], 1);
      if (pos < cap) {
        const int r = (int)ei[e];
        ushort4 rv;
        rv.x = fr(cv(x[r]));
        rv.y = fr(cv(ea[(size_t)3 * e + 0]));
        rv.z = fr(cv(ea[(size_t)3 * e + 1]));
        rv.w = fr(cv(ea[(size_t)3 * e + 2]));
        recB[pos] = rv;
        cid[pos] = (unsigned char)(c & 31);
      }
    }
  }
}

__global__ __launch_bounds__(256) void scatter_kernel(
    const void* xv, const void* eiv, const void* eav, const float* ws,
    const int* gcnt, const int* bstart, ushort4* recB, unsigned char* cid,
    const int E, const int NB, const int gb0, const int gb1, const int cap)
{
  __shared__ int lb[MAXNB];
  const int* fl = (const int*)(ws + OFF_FLAGS);
  const int ft = fl[0], it = fl[1];
  if (ft) {
    if (it) scatter_impl<__hip_bfloat16, long long>((const __hip_bfloat16*)xv, (const long long*)eiv, (const __hip_bfloat16*)eav, gcnt, bstart, recB, cid, lb, E, NB, gb0, gb1, cap);
    else    scatter_impl<__hip_bfloat16, int>((const __hip_bfloat16*)xv, (const int*)eiv, (const __hip_bfloat16*)eav, gcnt, bstart, recB, cid, lb, E, NB, gb0, gb1, cap);
  } else {
    if (it) scatter_impl<float, long long>((const float*)xv, (const long long*)eiv, (const float*)eav, gcnt, bstart, recB, cid, lb, E, NB, gb0, gb1, cap);
    else    scatter_impl<float, int>((const float*)xv, (const int*)eiv, (const float*)eav, gcnt, bstart, recB, cid, lb, E, NB, gb0, gb1, cap);
  }
}

// ---------------------------------------------------------------------------
// fused (cooperative MFMA): block owns bucket gb0+blockIdx.x. Per 64-edge
// tile, the 4 waves split the work: wave w = row-tile tm=w in GEMM1, and
// feature-slice tn2=w in GEMM2. agg lives in C2 registers across the whole
// bucket (no cross-wave atomics); deg rides in C3. One shared HT (9.2 KB).
// LDS ~22.5 KB -> 5-7 blocks/CU (vs r10's 54 KB -> 2).
// MFMA layouts (16x16x32 bf16): A[m=l15][k=quad*8+j], B[k=quad*8+j][n=l15],
// C/D[row=quad*4+reg][col=l15].
// ---------------------------------------------------------------------------
template<typename FT, typename IT>
__device__ __forceinline__ void fused_impl(
    const FT* __restrict__ x, const IT* __restrict__ batch,
    const float* __restrict__ ws, const int* __restrict__ bstart,
    const ushort4* __restrict__ recB, const unsigned char* __restrict__ cid,
    float* __restrict__ rep,
    short* sA, unsigned char* scid, short* sHT, short* aggB,
    float* pooledL, float* xls, unsigned short* xlsb, int* sbi,
    const int N, const int gb0, const int cap)
{
  const int t = threadIdx.x;
  const int lane = t & 63;
  const int quad = lane >> 4;
  const int l15 = lane & 15;
  const int wav = t >> 6;
  const int bucket = gb0 + blockIdx.x;

  for (int i = t; i < NGRAPH * 64; i += 256) pooledL[i] = 0.0f;
  if (t < BN) {
    const int n = bucket * BN + t;
    const float xvv = (n < N) ? cv(x[n]) : 0.0f;
    xls[t] = xvv;
    xlsb[t] = fr(xvv);
  }
  if (t == 0) {
    const int nf = bucket * BN, nl = bucket * BN + BN - 1;
    sbi[0] = (int)batch[(nf < N) ? nf : (N - 1)];
    sbi[1] = (int)batch[(nl < N) ? nl : (N - 1)];
    sbi[2] = bstart[gb0];
  }
  __syncthreads();

  // GEMM1 B fragments (W1 has k<8 only; quad>0 lanes carry zeros)
  const unsigned short* w1t = (const unsigned short*)(ws + OFF_W1T);
  short8 B1[4];
  #pragma unroll
  for (int tn = 0; tn < 4; ++tn) {
    short8 z; for (int j = 0; j < 8; ++j) z[j] = 0;
    if (quad == 0) z = *(const short8*)(w1t + (16 * tn + l15) * 8);
    B1[tn] = z;
  }
  short8 ONES8;
  #pragma unroll
  for (int j = 0; j < 8; ++j) ONES8[j] = (short)0x3F80;

  const int base = sbi[2];
  int s0 = bstart[bucket] - base;
  int e0 = bstart[bucket + 1] - base;
  if (s0 > cap) s0 = cap;
  if (e0 > cap) e0 = cap;

  // per-wave accumulators: agg[node][feat 16*wav+l15] and deg
  f32x4 C2[2]; C2[0] = (f32x4)0.0f; C2[1] = (f32x4)0.0f;
  f32x4 C3[2]; C3[0] = (f32x4)0.0f; C3[1] = (f32x4)0.0f;

  const int nedge = e0 - s0;
  const int nst = (nedge + 255) >> 8;
  for (int st = 0; st < nst; ++st) {
    // stage 256 edges cooperatively (fully coalesced)
    {
      const int idx = s0 + st * 256 + t;
      const bool valid = idx < e0;
      ushort4 rv = valid ? recB[idx] : make_ushort4(0, 0, 0, 0);
      const int c = valid ? (int)cid[idx] : 255;
      short8 row;
      row[0] = (short)rv.x;
      row[1] = valid ? (short)xlsb[c] : (short)0;
      row[2] = (short)rv.y; row[3] = (short)rv.z; row[4] = (short)rv.w;
      row[5] = valid ? (short)0x3F80 : (short)0;   // constant-1 col -> eb1
      row[6] = 0; row[7] = 0;
      *(short8*)(sA + t * 8) = row;
      scid[t] = (unsigned char)c;
    }
    __syncthreads();

    const int m = nedge - st * 256;
    const int jmax = (m >= 256) ? 4 : ((m + 63) >> 6);
    for (int j = 0; j < jmax; ++j) {
      // GEMM1: wave w computes H rows (edges 16*wav..+15 of tile j)
      short8 a1;
      if (quad == 0) a1 = *(const short8*)(sA + (j * 64 + 16 * wav + l15) * 8);
      else { for (int jj = 0; jj < 8; ++jj) a1[jj] = 0; }
      f32x4 Hc[4];
      #pragma unroll
      for (int tn = 0; tn < 4; ++tn)
        Hc[tn] = __builtin_amdgcn_mfma_f32_16x16x32_bf16(a1, B1[tn], (f32x4)0.0f, 0, 0, 0);
      // relu + fast-round + pack -> shared HT [feat][edge], stride 72 shorts
      #pragma unroll
      for (int tn = 0; tn < 4; ++tn) {
        uint2 pk;
        pk.x = rndpack(Hc[tn][0], Hc[tn][1]);
        pk.y = rndpack(Hc[tn][2], Hc[tn][3]);
        *(uint2*)(sHT + (16 * tn + l15) * 72 + 16 * wav + quad * 4) = pk;
      }
      __syncthreads();

      // GEMM2 (wave's feature slice tn2=wav): agg += S @ H ; deg += S @ 1
      const unsigned* sp = (const unsigned*)(scid + j * 64);
      #pragma unroll
      for (int q = 0; q < 2; ++q) {
        const unsigned lo = sp[2 * quad + 8 * q];
        const unsigned hi = sp[2 * quad + 8 * q + 1];
        short8 a2[2];
        #pragma unroll
        for (int tm2 = 0; tm2 < 2; ++tm2) {
          const int seg = 16 * tm2 + l15;
          short8 v;
          v[0] = (((lo      ) & 255u) == (unsigned)seg) ? (short)0x3F80 : (short)0;
          v[1] = (((lo >>  8) & 255u) == (unsigned)seg) ? (short)0x3F80 : (short)0;
          v[2] = (((lo >> 16) & 255u) == (unsigned)seg) ? (short)0x3F80 : (short)0;
          v[3] = (((lo >> 24) & 255u) == (unsigned)seg) ? (short)0x3F80 : (short)0;
          v[4] = (((hi      ) & 255u) == (unsigned)seg) ? (short)0x3F80 : (short)0;
          v[5] = (((hi >>  8) & 255u) == (unsigned)seg) ? (short)0x3F80 : (short)0;
          v[6] = (((hi >> 16) & 255u) == (unsigned)seg) ? (short)0x3F80 : (short)0;
          v[7] = (((hi >> 24) & 255u) == (unsigned)seg) ? (short)0x3F80 : (short)0;
          a2[tm2] = v;
        }
        const short8 b2 = *(const short8*)(sHT + (16 * wav + l15) * 72 + 32 * q + quad * 8);
        C2[0] = __builtin_amdgcn_mfma_f32_16x16x32_bf16(a2[0], b2, C2[0], 0, 0, 0);
        C2[1] = __builtin_amdgcn_mfma_f32_16x16x32_bf16(a2[1], b2, C2[1], 0, 0, 0);
        C3[0] = __builtin_amdgcn_mfma_f32_16x16x32_bf16(a2[0], ONES8, C3[0], 0, 0, 0);
        C3[1] = __builtin_amdgcn_mfma_f32_16x16x32_bf16(a2[1], ONES8, C3[1], 0, 0, 0);
      }
      __syncthreads();
    }
  }

  // dump agg to LDS (bf16) for the node GEMM A-operand
  #pragma unroll
  for (int tm2 = 0; tm2 < 2; ++tm2) {
    #pragma unroll
    for (int r = 0; r < 4; ++r)
      aggB[(16 * tm2 + quad * 4 + r) * 72 + 16 * wav + l15] = (short)fr(C2[tm2][r]);
  }
  __syncthreads();

  // node GEMM: wave w computes D[32 nodes][feats 16w..16w+15] = agg @ M
  const unsigned short* mt = (const unsigned short*)(ws + OFF_MT);
  f32x4 D[2]; D[0] = (f32x4)0.0f; D[1] = (f32x4)0.0f;
  #pragma unroll
  for (int q2 = 0; q2 < 2; ++q2) {
    const short8 bb = *(const short8*)(mt + (16 * wav + l15) * 64 + 32 * q2 + quad * 8);
    #pragma unroll
    for (int tm2 = 0; tm2 < 2; ++tm2) {
      const short8 aa = *(const short8*)(aggB + (16 * tm2 + l15) * 72 + 32 * q2 + quad * 8);
      D[tm2] = __builtin_amdgcn_mfma_f32_16x16x32_bf16(aa, bb, D[tm2], 0, 0, 0);
    }
  }

  // epilogue: h = relu(D + x*c1 + deg*v + nb1); pool by graph (deg = C3 regs)
  const int n = 16 * wav + l15;
  const float c1n = ws[OFF_NW1 + n];
  const float vn  = ws[OFF_V + n];
  const float bn  = ws[OFF_NB1 + n];
  #pragma unroll
  for (int tm2 = 0; tm2 < 2; ++tm2) {
    #pragma unroll
    for (int r = 0; r < 4; ++r) {
      const int mrow = 16 * tm2 + quad * 4 + r;
      const int ng = bucket * BN + mrow;
      if (ng < N) {
        const float h = fmaxf(D[tm2][r] + xls[mrow] * c1n + C3[tm2][r] * vn + bn, 0.0f);
        const int g = (int)batch[ng];
        atomicAdd(&pooledL[g * 64 + n], h);
      }
    }
  }
  __syncthreads();

  float* myrep = rep + (size_t)(bucket & 7) * (NGRAPH * 64);
  for (int g = sbi[0] + wav; g <= sbi[1]; g += 4)
    unsafeAtomicAdd(&myrep[g * 64 + lane], pooledL[g * 64 + lane]);
}

__global__ __launch_bounds__(256) void fused_kernel(
    const void* xv, const void* batv, const float* ws, const int* bstart,
    const ushort4* recB, const unsigned char* cid, float* rep,
    const int N, const int gb0, const int cap)
{
  // LDS hoisted here (one copy across template instantiations): ~22.5 KB
  __shared__ __align__(16) short sA[256 * 8];            // 4 KB
  __shared__ __align__(8)  unsigned char scid[256];      // 256 B
  __shared__ __align__(16) short sHT[64 * 72];           // 9.2 KB (shared, 1 tile)
  __shared__ __align__(16) short aggB[32 * 72];          // 4.6 KB
  __shared__ float pooledL[NGRAPH * 64];                 // 4 KB
  __shared__ float xls[BN];
  __shared__ unsigned short xlsb[BN];
  __shared__ int   sbi[3];

  const int* fl = (const int*)(ws + OFF_FLAGS);
  const int ft = fl[0], it = fl[1];
  if (ft) {
    if (it) fused_impl<__hip_bfloat16, long long>((const __hip_bfloat16*)xv, (const long long*)batv, ws, bstart, recB, cid, rep, sA, scid, sHT, aggB, pooledL, xls, xlsb, sbi, N, gb0, cap);
    else    fused_impl<__hip_bfloat16, int>((const __hip_bfloat16*)xv, (const int*)batv, ws, bstart, recB, cid, rep, sA, scid, sHT, aggB, pooledL, xls, xlsb, sbi, N, gb0, cap);
  } else {
    if (it) fused_impl<float, long long>((const float*)xv, (const long long*)batv, ws, bstart, recB, cid, rep, sA, scid, sHT, aggB, pooledL, xls, xlsb, sbi, N, gb0, cap);
    else    fused_impl<float, int>((const float*)xv, (const int*)batv, ws, bstart, recB, cid, rep, sA, scid, sHT, aggB, pooledL, xls, xlsb, sbi, N, gb0, cap);
  }
}

// ---------------------------------------------------------------------------
// head: reduce 8 pooled replicas; cnt via sorted-boundary detection; dense head.
// ---------------------------------------------------------------------------
__global__ __launch_bounds__(256) void head_kernel(
    const float* ws, const float* rep, const void* batv, void* outv, const int N)
{
  __shared__ float P[NGRAPH][HID];
  __shared__ float A[NGRAPH][HID];
  __shared__ float B[NGRAPH][HID];
  __shared__ int endL[NGRAPH];

  const int t = threadIdx.x;
  const int j = t & 63;
  const int gq = t >> 6;

  const int it = ((const int*)(ws + OFF_FLAGS))[1];
  if (it) {
    const long long* bt = (const long long*)batv;
    for (int i = t; i < N; i += 256) {
      const int g1 = (int)bt[i];
      if (i == 0) for (int g = 0; g < g1; ++g) endL[g] = 0;
      if (i == N - 1) { for (int g = g1; g < NGRAPH; ++g) endL[g] = N; }
      else {
        const int g2 = (int)bt[i + 1];
        for (int g = g1; g < g2; ++g) endL[g] = i + 1;
      }
    }
  } else {
    const int* bt = (const int*)batv;
    for (int i = t; i < N; i += 256) {
      const int g1 = bt[i];
      if (i == 0) for (int g = 0; g < g1; ++g) endL[g] = 0;
      if (i == N - 1) { for (int g = g1; g < NGRAPH; ++g) endL[g] = N; }
      else {
        const int g2 = bt[i + 1];
        for (int g = g1; g < g2; ++g) endL[g] = i + 1;
      }
    }
  }

  #pragma unroll
  for (int gi = 0; gi < 4; ++gi) {
    const int g = gq + gi * 4;
    float s = 0.0f;
    #pragma unroll
    for (int r = 0; r < 8; ++r)
      s += rep[(size_t)r * (NGRAPH * 64) + g * 64 + j];
    P[g][j] = s;
  }
  __syncthreads();

  {
    const float bj = ws[OFF_NB2 + j];
    #pragma unroll
    for (int gi = 0; gi < 4; ++gi) {
      const int g = gq + gi * 4;
      const float cg = (float)(endL[g] - (g ? endL[g - 1] : 0));
      float s = cg * bj;
      #pragma unroll 8
      for (int k = 0; k < HID; ++k)
        s = fmaf(P[g][k], ws[OFF_NW2 + k * HID + j], s);
      A[g][j] = s;
    }
  }
  __syncthreads();

  const int wOff[3] = {OFF_OW1, OFF_OW2, OFF_OW3};
  const int bOff[3] = {OFF_OB1, OFF_OB2, OFF_OB3};
  for (int L = 0; L < 3; ++L) {
    float (*In)[HID]  = (L & 1) ? B : A;
    float (*Out)[HID] = (L & 1) ? A : B;
    const float bj = ws[bOff[L] + j];
    #pragma unroll
    for (int gi = 0; gi < 4; ++gi) {
      const int g = gq + gi * 4;
      float s = bj;
      #pragma unroll 8
      for (int k = 0; k < HID; ++k)
        s = fmaf(In[g][k], ws[wOff[L] + k * HID + j], s);
      Out[g][j] = fmaxf(s, 0.0f);
    }
    __syncthreads();
  }

  if (t < 32) {
    const int g = t >> 1, d = t & 1;
    float s = ws[OFF_OB4 + d];
    #pragma unroll 8
    for (int k = 0; k < HID; ++k)
      s = fmaf(B[g][k], ws[OFF_OW4 + k * 2 + d], s);
    const int ft = ((const int*)(ws + OFF_FLAGS))[0];
    if (ft) ((__hip_bfloat16*)outv)[g * 2 + d] = __float2bfloat16(s);
    else    ((float*)outv)[g * 2 + d] = s;
  }
}

extern "C" void kernel_launch(void* const* d_in, const int* in_sizes, int n_in,
                              void* d_out, int out_size, void* d_ws, size_t ws_size,
                              hipStream_t stream)
{
  const void* xv   = d_in[0];
  const void* eiv  = d_in[1];
  const void* eav  = d_in[2];
  const void* batv = d_in[3];

  WPtrs wp;
  for (int a = 0; a < 16; ++a) wp.p[a] = d_in[4 + a];

  const int N = in_sizes[0];
  const int E = in_sizes[1] / 2;
  const int NB = (N + BN - 1) / BN;
  if (NB > MAXNB) return;

  float* ws   = (float*)d_ws;
  float* rep  = ws + OFF_PREP;                             // 8*1024 floats
  int* bstart = (int*)(rep + 8 * NGRAPH * 64);             // NB+1 ints
  int* gcnt   = bstart + NB + 1;                           // NB*NCB ints

  size_t recOffB = ((size_t)((char*)(gcnt + (size_t)NB * NCB) - (char*)d_ws) + 15) & ~(size_t)15;

  int G = -1; long long cap = 0;
  for (int g = 1; g <= 64; ++g) {
    const long long c = (long long)E / g + E / 32 + 8192;
    if (recOffB + (size_t)c * 9 <= ws_size) { G = g; cap = c; break; }
  }
  if (G < 0) return;

  ushort4* recB = (ushort4*)((char*)d_ws + recOffB);
  unsigned char* cid = (unsigned char*)(recB + cap);
  const int gsz = (NB + G - 1) / G;
  const int sblk = (NB + 3) / 4;

  hipMemsetAsync(rep, 0, (size_t)(8 * NGRAPH * 64) * 4, stream);

  prep_kernel<<<1, 256, 0, stream>>>(xv, eiv, wp, ws);
  count_kernel<<<NCB, 256, 0, stream>>>(eiv, ws, gcnt, E, NB);
  scan_tot_kernel<<<sblk, 256, 0, stream>>>(gcnt, bstart, NB);
  scan_pref_kernel<<<1, 256, 0, stream>>>(bstart, NB);
  scan_row_kernel<<<sblk, 256, 0, stream>>>(gcnt, bstart, NB);

  for (int g = 0; g < G; ++g) {
    const int gb0 = g * gsz;
    const int gb1 = (gb0 + gsz < NB) ? (gb0 + gsz) : NB;
    if (gb0 >= gb1) break;
    scatter_kernel<<<NCB, 256, 0, stream>>>(xv, eiv, eav, ws, gcnt, bstart,
                                            recB, cid, E, NB, gb0, gb1, (int)cap);
    fused_kernel<<<gb1 - gb0, 256, 0, stream>>>(xv, batv, ws, bstart, recB, cid,
                                                rep, N, gb0, (int)cap);
  }

  head_kernel<<<1, 256, 0, stream>>>(ws, rep, batv, d_out, N);
}

// Round 13
// 314.976 us; speedup vs baseline: 3.6048x; 1.2564x over previous
//
#include <hip/hip_runtime.h>
#include <hip/hip_bf16.h>

#define HID 64
#define NGRAPH 16
#define BN 32            // nodes per bucket
#define MAXNB 2048
#define NCB 256          // count/scatter blocks

typedef __attribute__((ext_vector_type(8))) short short8;
typedef __attribute__((ext_vector_type(4))) float f32x4;

// Fixed workspace layout (float offsets)
enum : int {
  OFF_V      = 1040,
  OFF_M      = 1104,
  OFF_EW1    = 5200,
  OFF_EB1    = 5520,
  OFF_NW1    = 5584,
  OFF_NB1    = 9744,
  OFF_NW2    = 9808,
  OFF_NB2    = 13904,
  OFF_OW1    = 13968,
  OFF_OB1    = 18064,
  OFF_OW2    = 18128,
  OFF_OB2    = 22224,
  OFF_OW3    = 22288,
  OFF_OB3    = 26384,
  OFF_OW4    = 26448,
  OFF_OB4    = 26576,
  OFF_EW2    = 26578,
  OFF_EB2    = 30674,
  OFF_FLAGS  = 30738,                 // 2 ints: [0]=ft (1=bf16), [1]=it (1=int64)
  OFF_W1T    = 30740,                 // 512 shorts (64 feats x 8 k)
  OFF_MT     = 30996,                 // 4096 shorts (M^T bf16)
  OFF_PREP   = 33044                  // rep: 8 pooled replicas * 16*64
};

struct WPtrs { const void* p[16]; };

__device__ __forceinline__ float cv(float v) { return v; }
__device__ __forceinline__ float cv(__hip_bfloat16 v) { return __bfloat162float(v); }
__device__ __forceinline__ unsigned short f2bu(float v) {   // cold path only
  union { __hip_bfloat16 b; unsigned short u; } c;
  c.b = __float2bfloat16(v);
  return c.u;
}
// fast RNE f32->bf16 (finite inputs): 3 VALU inst
__device__ __forceinline__ unsigned short fr(float v) {
  unsigned u = __float_as_uint(v);
  u += 0x7FFFu + ((u >> 16) & 1u);
  return (unsigned short)(u >> 16);
}
// relu + RNE-round two floats, pack into one dword (lo = a, hi = b)
__device__ __forceinline__ unsigned rndpack(float a, float b) {
  unsigned ua = __float_as_uint(fmaxf(a, 0.0f));
  unsigned ub = __float_as_uint(fmaxf(b, 0.0f));
  ua += 0x7FFFu + ((ua >> 16) & 1u);
  ub += 0x7FFFu + ((ub >> 16) & 1u);
  return __builtin_amdgcn_perm(ub, ua, 0x07060302u);
}

// ---------------------------------------------------------------------------
// prep: detect dtypes, convert weights to fp32, build folded M, v, W1T, MT.
// ---------------------------------------------------------------------------
__global__ __launch_bounds__(256) void prep_kernel(
    const void* xv, const void* eiv, WPtrs wp, float* ws)
{
  __shared__ int red[2];
  __shared__ int s_ft;
  __shared__ float ew2s[4096];
  __shared__ float nw1s[4096];
  const int t = threadIdx.x;

  if (t == 0) { red[0] = 0; red[1] = 0; }
  __syncthreads();
  {
    const unsigned* u = (const unsigned*)xv;
    int big = 0;
    for (int i = t; i < 512; i += 256) {
      const unsigned el = (u[i] >> 7) & 0xFFu;
      big += (el >= 140u) ? 1 : 0;
    }
    atomicAdd(&red[0], big);
  }
  {
    const int* e32 = (const int*)eiv;
    int orv = 0;
    for (int i = 1 + 2 * t; i < 2048; i += 512) orv |= e32[i];
    atomicOr(&red[1], orv);
  }
  __syncthreads();
  if (t == 0) {
    const int ft = (red[0] < 8) ? 1 : 0;
    const int it = (red[1] == 0) ? 1 : 0;
    ((int*)(ws + OFF_FLAGS))[0] = ft;
    ((int*)(ws + OFF_FLAGS))[1] = it;
    s_ft = ft;
  }
  __syncthreads();
  const int ft = s_ft;

  const int sz[16]  = {320,64,4096,64,4160,64,4096,64,4096,64,4096,64,4096,64,128,2};
  const int dst[16] = {OFF_EW1,OFF_EB1,OFF_EW2,OFF_EB2,OFF_NW1,OFF_NB1,OFF_NW2,OFF_NB2,
                       OFF_OW1,OFF_OB1,OFF_OW2,OFF_OB2,OFF_OW3,OFF_OB3,OFF_OW4,OFF_OB4};
  for (int a = 0; a < 16; ++a) {
    const void* src = wp.p[a];
    float* d = ws + dst[a];
    const int n = sz[a];
    for (int i = t; i < n; i += 256)
      d[i] = ft ? __bfloat162float(((const __hip_bfloat16*)src)[i])
                : ((const float*)src)[i];
  }
  __syncthreads();

  for (int i = t; i < 4096; i += 256) {
    ew2s[i] = ws[OFF_EW2 + i];
    nw1s[i] = ws[OFF_NW1 + 64 + i];
  }
  __syncthreads();
  for (int idx = t; idx < 4096; idx += 256) {
    const int i = idx >> 6, j = idx & 63;
    float s = 0.0f;
    #pragma unroll 8
    for (int k = 0; k < 64; ++k)
      s = fmaf(ew2s[i * 64 + k], nw1s[k * 64 + j], s);
    ws[OFF_M + idx] = s;
  }
  for (int j = t; j < 64; j += 256) {
    float s = 0.0f;
    #pragma unroll 8
    for (int k = 0; k < 64; ++k)
      s = fmaf(ws[OFF_EB2 + k], nw1s[k * 64 + j], s);
    ws[OFF_V + j] = s;
  }
  __syncthreads();

  unsigned short* w1t = (unsigned short*)(ws + OFF_W1T);
  for (int n = t; n < 64; n += 256) {
    #pragma unroll
    for (int k = 0; k < 8; ++k) {
      float v = 0.0f;
      if (k < 5) v = ws[OFF_EW1 + k * 64 + n];
      else if (k == 5) v = ws[OFF_EB1 + n];
      w1t[n * 8 + k] = f2bu(v);
    }
  }
  unsigned short* mt = (unsigned short*)(ws + OFF_MT);
  for (int idx = t; idx < 4096; idx += 256) {
    const int n = idx >> 6, k = idx & 63;
    mt[idx] = f2bu(ws[OFF_M + k * 64 + n]);
  }
}

// ---------------------------------------------------------------------------
// bounds: parallel graph-boundary detection over sorted batch -> endG[16].
// Each of the 16 slots is written by exactly one thread (no atomics).
// (r11: this loop inside single-block head_kernel was the 132 us top dispatch)
// ---------------------------------------------------------------------------
template<typename IT>
__device__ __forceinline__ void bounds_impl(
    const IT* __restrict__ bt, int* __restrict__ endG, const int N)
{
  const int i = blockIdx.x * 256 + threadIdx.x;
  if (i >= N) return;
  const int g1 = (int)bt[i];
  if (i == 0) for (int g = 0; g < g1; ++g) endG[g] = 0;
  if (i == N - 1) {
    for (int g = g1; g < NGRAPH; ++g) endG[g] = N;
  } else {
    const int g2 = (int)bt[i + 1];
    for (int g = g1; g < g2; ++g) endG[g] = i + 1;
  }
}

__global__ __launch_bounds__(256) void bounds_kernel(
    const void* batv, const float* ws, int* endG, const int N)
{
  const int it = ((const int*)(ws + OFF_FLAGS))[1];
  if (it) bounds_impl<long long>((const long long*)batv, endG, N);
  else    bounds_impl<int>((const int*)batv, endG, N);
}

// ---------------------------------------------------------------------------
// count: per-block LDS histogram; gcnt[bucket*NCB + block] (bucket-major).
// ---------------------------------------------------------------------------
template<typename IT>
__device__ __forceinline__ void count_impl(
    const IT* __restrict__ ei, int* __restrict__ gcnt, int* lh,
    const int E, const int NB)
{
  const int t = threadIdx.x;
  const int b = blockIdx.x;
  for (int i = t; i < NB; i += 256) lh[i] = 0;
  __syncthreads();
  const int per = (E + NCB - 1) / NCB;
  const int a = b * per;
  const int bnd = (a + per < E) ? (a + per) : E;
  for (int e = a + t; e < bnd; e += 256) {
    const int c = (int)ei[(size_t)E + e];
    atomicAdd(&lh[c >> 5], 1);
  }
  __syncthreads();
  for (int i = t; i < NB; i += 256) gcnt[(size_t)i * NCB + b] = lh[i];
}

__global__ __launch_bounds__(256) void count_kernel(
    const void* eiv, const float* ws, int* gcnt, const int E, const int NB)
{
  __shared__ int lh[MAXNB];
  const int it = ((const int*)(ws + OFF_FLAGS))[1];
  if (it) count_impl<long long>((const long long*)eiv, gcnt, lh, E, NB);
  else    count_impl<int>((const int*)eiv, gcnt, lh, E, NB);
}

// ---------------------------------------------------------------------------
// scan (3-kernel parallel version, r10-verified)
// ---------------------------------------------------------------------------
__global__ __launch_bounds__(256) void scan_tot_kernel(
    const int* __restrict__ gcnt, int* __restrict__ bstart, const int NB)
{
  const int lane = threadIdx.x & 63;
  const int bkt = blockIdx.x * 4 + (threadIdx.x >> 6);
  if (bkt >= NB) return;
  const int4 v = *(const int4*)(gcnt + (size_t)bkt * NCB + lane * 4);
  int s = v.x + v.y + v.z + v.w;
  #pragma unroll
  for (int off = 32; off > 0; off >>= 1) s += __shfl_xor(s, off);
  if (lane == 0) bstart[bkt] = s;
}

__global__ __launch_bounds__(256) void scan_pref_kernel(
    int* __restrict__ bstart, const int NB)
{
  __shared__ int ps[256];
  const int t = threadIdx.x;
  const int seg = (NB + 255) / 256;
  int s = 0;
  for (int i = 0; i < seg; ++i) {
    const int idx = t * seg + i;
    if (idx < NB) s += bstart[idx];
  }
  ps[t] = s;
  __syncthreads();
  for (int off = 1; off < 256; off <<= 1) {
    const int v = (t >= off) ? ps[t - off] : 0;
    __syncthreads();
    ps[t] += v;
    __syncthreads();
  }
  int carry = ps[t] - s;
  for (int i = 0; i < seg; ++i) {
    const int idx = t * seg + i;
    if (idx < NB) {
      const int c = bstart[idx];
      bstart[idx] = carry;
      carry += c;
    }
  }
  if (t == 255) bstart[NB] = ps[255];
}

__global__ __launch_bounds__(256) void scan_row_kernel(
    int* __restrict__ gcnt, const int* __restrict__ bstart, const int NB)
{
  const int lane = threadIdx.x & 63;
  const int bkt = blockIdx.x * 4 + (threadIdx.x >> 6);
  if (bkt >= NB) return;
  int* row = gcnt + (size_t)bkt * NCB;
  const int4 v = *(const int4*)(row + lane * 4);
  const int ls = v.x + v.y + v.z + v.w;
  int s = ls;
  #pragma unroll
  for (int off = 1; off < 64; off <<= 1) {
    const int u = __shfl_up(s, off);
    if (lane >= off) s += u;
  }
  int e = s - ls + bstart[bkt];
  int4 o;
  o.x = e; e += v.x;
  o.y = e; e += v.y;
  o.z = e; e += v.z;
  o.w = e;
  *(int4*)(row + lane * 4) = o;
}

// ---------------------------------------------------------------------------
// scatter (per group): write sorted bf16 payload recB[pos]={xr,a0,a1,a2} +
// cid[pos]=col&31 for buckets [gb0,gb1). LDS cursors; zero global atomics.
// ---------------------------------------------------------------------------
template<typename FT, typename IT>
__device__ __forceinline__ void scatter_impl(
    const FT* __restrict__ x, const IT* __restrict__ ei, const FT* __restrict__ ea,
    const int* __restrict__ gcnt, const int* __restrict__ bstart,
    ushort4* __restrict__ recB, unsigned char* __restrict__ cid, int* lb,
    const int E, const int NB, const int gb0, const int gb1, const int cap)
{
  const int t = threadIdx.x;
  const int b = blockIdx.x;
  __shared__ int sbase;
  if (t == 0) sbase = bstart[gb0];
  __syncthreads();
  const int base = sbase;
  const int gcount = gb1 - gb0;
  for (int i = t; i < gcount; i += 256) lb[i] = gcnt[(size_t)(gb0 + i) * NCB + b] - base;
  __syncthreads();

  const int per = (E + NCB - 1) / NCB;
  const int a = b * per;
  const int bnd = (a + per < E) ? (a + per) : E;
  for (int e = a + t; e < bnd; e += 256) {
    const int c = (int)ei[(size_t)E + e];
    const int bkt = c >> 5;
    if (bkt >= gb0 && bkt < gb1) {
      const int pos = atomicAdd(&lb[bkt - gb0], 1);
      if (pos < cap) {
        const int r = (int)ei[e];
        ushort4 rv;
        rv.x = fr(cv(x[r]));
        rv.y = fr(cv(ea[(size_t)3 * e + 0]));
        rv.z = fr(cv(ea[(size_t)3 * e + 1]));
        rv.w = fr(cv(ea[(size_t)3 * e + 2]));
        recB[pos] = rv;
        cid[pos] = (unsigned char)(c & 31);
      }
    }
  }
}

__global__ __launch_bounds__(256) void scatter_kernel(
    const void* xv, const void* eiv, const void* eav, const float* ws,
    const int* gcnt, const int* bstart, ushort4* recB, unsigned char* cid,
    const int E, const int NB, const int gb0, const int gb1, const int cap)
{
  __shared__ int lb[MAXNB];
  const int* fl = (const int*)(ws + OFF_FLAGS);
  const int ft = fl[0], it = fl[1];
  if (ft) {
    if (it) scatter_impl<__hip_bfloat16, long long>((const __hip_bfloat16*)xv, (const long long*)eiv, (const __hip_bfloat16*)eav, gcnt, bstart, recB, cid, lb, E, NB, gb0, gb1, cap);
    else    scatter_impl<__hip_bfloat16, int>((const __hip_bfloat16*)xv, (const int*)eiv, (const __hip_bfloat16*)eav, gcnt, bstart, recB, cid, lb, E, NB, gb0, gb1, cap);
  } else {
    if (it) scatter_impl<float, long long>((const float*)xv, (const long long*)eiv, (const float*)eav, gcnt, bstart, recB, cid, lb, E, NB, gb0, gb1, cap);
    else    scatter_impl<float, int>((const float*)xv, (const int*)eiv, (const float*)eav, gcnt, bstart, recB, cid, lb, E, NB, gb0, gb1, cap);
  }
}

// ---------------------------------------------------------------------------
// fused (cooperative MFMA, r11-verified): block owns bucket gb0+blockIdx.x.
// Waves split each 64-edge tile; agg lives in C2 registers; deg in C3.
// ---------------------------------------------------------------------------
template<typename FT, typename IT>
__device__ __forceinline__ void fused_impl(
    const FT* __restrict__ x, const IT* __restrict__ batch,
    const float* __restrict__ ws, const int* __restrict__ bstart,
    const ushort4* __restrict__ recB, const unsigned char* __restrict__ cid,
    float* __restrict__ rep,
    short* sA, unsigned char* scid, short* sHT, short* aggB,
    float* pooledL, float* xls, unsigned short* xlsb, int* sbi,
    const int N, const int gb0, const int cap)
{
  const int t = threadIdx.x;
  const int lane = t & 63;
  const int quad = lane >> 4;
  const int l15 = lane & 15;
  const int wav = t >> 6;
  const int bucket = gb0 + blockIdx.x;

  for (int i = t; i < NGRAPH * 64; i += 256) pooledL[i] = 0.0f;
  if (t < BN) {
    const int n = bucket * BN + t;
    const float xvv = (n < N) ? cv(x[n]) : 0.0f;
    xls[t] = xvv;
    xlsb[t] = fr(xvv);
  }
  if (t == 0) {
    const int nf = bucket * BN, nl = bucket * BN + BN - 1;
    sbi[0] = (int)batch[(nf < N) ? nf : (N - 1)];
    sbi[1] = (int)batch[(nl < N) ? nl : (N - 1)];
    sbi[2] = bstart[gb0];
  }
  __syncthreads();

  const unsigned short* w1t = (const unsigned short*)(ws + OFF_W1T);
  short8 B1[4];
  #pragma unroll
  for (int tn = 0; tn < 4; ++tn) {
    short8 z; for (int j = 0; j < 8; ++j) z[j] = 0;
    if (quad == 0) z = *(const short8*)(w1t + (16 * tn + l15) * 8);
    B1[tn] = z;
  }
  short8 ONES8;
  #pragma unroll
  for (int j = 0; j < 8; ++j) ONES8[j] = (short)0x3F80;

  const int base = sbi[2];
  int s0 = bstart[bucket] - base;
  int e0 = bstart[bucket + 1] - base;
  if (s0 > cap) s0 = cap;
  if (e0 > cap) e0 = cap;

  f32x4 C2[2]; C2[0] = (f32x4)0.0f; C2[1] = (f32x4)0.0f;
  f32x4 C3[2]; C3[0] = (f32x4)0.0f; C3[1] = (f32x4)0.0f;

  const int nedge = e0 - s0;
  const int nst = (nedge + 255) >> 8;
  for (int st = 0; st < nst; ++st) {
    {
      const int idx = s0 + st * 256 + t;
      const bool valid = idx < e0;
      ushort4 rv = valid ? recB[idx] : make_ushort4(0, 0, 0, 0);
      const int c = valid ? (int)cid[idx] : 255;
      short8 row;
      row[0] = (short)rv.x;
      row[1] = valid ? (short)xlsb[c] : (short)0;
      row[2] = (short)rv.y; row[3] = (short)rv.z; row[4] = (short)rv.w;
      row[5] = valid ? (short)0x3F80 : (short)0;
      row[6] = 0; row[7] = 0;
      *(short8*)(sA + t * 8) = row;
      scid[t] = (unsigned char)c;
    }
    __syncthreads();

    const int m = nedge - st * 256;
    const int jmax = (m >= 256) ? 4 : ((m + 63) >> 6);
    for (int j = 0; j < jmax; ++j) {
      short8 a1;
      if (quad == 0) a1 = *(const short8*)(sA + (j * 64 + 16 * wav + l15) * 8);
      else { for (int jj = 0; jj < 8; ++jj) a1[jj] = 0; }
      f32x4 Hc[4];
      #pragma unroll
      for (int tn = 0; tn < 4; ++tn)
        Hc[tn] = __builtin_amdgcn_mfma_f32_16x16x32_bf16(a1, B1[tn], (f32x4)0.0f, 0, 0, 0);
      #pragma unroll
      for (int tn = 0; tn < 4; ++tn) {
        uint2 pk;
        pk.x = rndpack(Hc[tn][0], Hc[tn][1]);
        pk.y = rndpack(Hc[tn][2], Hc[tn][3]);
        *(uint2*)(sHT + (16 * tn + l15) * 72 + 16 * wav + quad * 4) = pk;
      }
      __syncthreads();

      const unsigned* sp = (const unsigned*)(scid + j * 64);
      #pragma unroll
      for (int q = 0; q < 2; ++q) {
        const unsigned lo = sp[2 * quad + 8 * q];
        const unsigned hi = sp[2 * quad + 8 * q + 1];
        short8 a2[2];
        #pragma unroll
        for (int tm2 = 0; tm2 < 2; ++tm2) {
          const int seg = 16 * tm2 + l15;
          short8 v;
          v[0] = (((lo      ) & 255u) == (unsigned)seg) ? (short)0x3F80 : (short)0;
          v[1] = (((lo >>  8) & 255u) == (unsigned)seg) ? (short)0x3F80 : (short)0;
          v[2] = (((lo >> 16) & 255u) == (unsigned)seg) ? (short)0x3F80 : (short)0;
          v[3] = (((lo >> 24) & 255u) == (unsigned)seg) ? (short)0x3F80 : (short)0;
          v[4] = (((hi      ) & 255u) == (unsigned)seg) ? (short)0x3F80 : (short)0;
          v[5] = (((hi >>  8) & 255u) == (unsigned)seg) ? (short)0x3F80 : (short)0;
          v[6] = (((hi >> 16) & 255u) == (unsigned)seg) ? (short)0x3F80 : (short)0;
          v[7] = (((hi >> 24) & 255u) == (unsigned)seg) ? (short)0x3F80 : (short)0;
          a2[tm2] = v;
        }
        const short8 b2 = *(const short8*)(sHT + (16 * wav + l15) * 72 + 32 * q + quad * 8);
        C2[0] = __builtin_amdgcn_mfma_f32_16x16x32_bf16(a2[0], b2, C2[0], 0, 0, 0);
        C2[1] = __builtin_amdgcn_mfma_f32_16x16x32_bf16(a2[1], b2, C2[1], 0, 0, 0);
        C3[0] = __builtin_amdgcn_mfma_f32_16x16x32_bf16(a2[0], ONES8, C3[0], 0, 0, 0);
        C3[1] = __builtin_amdgcn_mfma_f32_16x16x32_bf16(a2[1], ONES8, C3[1], 0, 0, 0);
      }
      __syncthreads();
    }
  }

  #pragma unroll
  for (int tm2 = 0; tm2 < 2; ++tm2) {
    #pragma unroll
    for (int r = 0; r < 4; ++r)
      aggB[(16 * tm2 + quad * 4 + r) * 72 + 16 * wav + l15] = (short)fr(C2[tm2][r]);
  }
  __syncthreads();

  const unsigned short* mt = (const unsigned short*)(ws + OFF_MT);
  f32x4 D[2]; D[0] = (f32x4)0.0f; D[1] = (f32x4)0.0f;
  #pragma unroll
  for (int q2 = 0; q2 < 2; ++q2) {
    const short8 bb = *(const short8*)(mt + (16 * wav + l15) * 64 + 32 * q2 + quad * 8);
    #pragma unroll
    for (int tm2 = 0; tm2 < 2; ++tm2) {
      const short8 aa = *(const short8*)(aggB + (16 * tm2 + l15) * 72 + 32 * q2 + quad * 8);
      D[tm2] = __builtin_amdgcn_mfma_f32_16x16x32_bf16(aa, bb, D[tm2], 0, 0, 0);
    }
  }

  const int n = 16 * wav + l15;
  const float c1n = ws[OFF_NW1 + n];
  const float vn  = ws[OFF_V + n];
  const float bn  = ws[OFF_NB1 + n];
  #pragma unroll
  for (int tm2 = 0; tm2 < 2; ++tm2) {
    #pragma unroll
    for (int r = 0; r < 4; ++r) {
      const int mrow = 16 * tm2 + quad * 4 + r;
      const int ng = bucket * BN + mrow;
      if (ng < N) {
        const float h = fmaxf(D[tm2][r] + xls[mrow] * c1n + C3[tm2][r] * vn + bn, 0.0f);
        const int g = (int)batch[ng];
        atomicAdd(&pooledL[g * 64 + n], h);
      }
    }
  }
  __syncthreads();

  float* myrep = rep + (size_t)(bucket & 7) * (NGRAPH * 64);
  for (int g = sbi[0] + wav; g <= sbi[1]; g += 4)
    unsafeAtomicAdd(&myrep[g * 64 + lane], pooledL[g * 64 + lane]);
}

__global__ __launch_bounds__(256) void fused_kernel(
    const void* xv, const void* batv, const float* ws, const int* bstart,
    const ushort4* recB, const unsigned char* cid, float* rep,
    const int N, const int gb0, const int cap)
{
  __shared__ __align__(16) short sA[256 * 8];            // 4 KB
  __shared__ __align__(8)  unsigned char scid[256];      // 256 B
  __shared__ __align__(16) short sHT[64 * 72];           // 9.2 KB
  __shared__ __align__(16) short aggB[32 * 72];          // 4.6 KB
  __shared__ float pooledL[NGRAPH * 64];                 // 4 KB
  __shared__ float xls[BN];
  __shared__ unsigned short xlsb[BN];
  __shared__ int   sbi[3];

  const int* fl = (const int*)(ws + OFF_FLAGS);
  const int ft = fl[0], it = fl[1];
  if (ft) {
    if (it) fused_impl<__hip_bfloat16, long long>((const __hip_bfloat16*)xv, (const long long*)batv, ws, bstart, recB, cid, rep, sA, scid, sHT, aggB, pooledL, xls, xlsb, sbi, N, gb0, cap);
    else    fused_impl<__hip_bfloat16, int>((const __hip_bfloat16*)xv, (const int*)batv, ws, bstart, recB, cid, rep, sA, scid, sHT, aggB, pooledL, xls, xlsb, sbi, N, gb0, cap);
  } else {
    if (it) fused_impl<float, long long>((const float*)xv, (const long long*)batv, ws, bstart, recB, cid, rep, sA, scid, sHT, aggB, pooledL, xls, xlsb, sbi, N, gb0, cap);
    else    fused_impl<float, int>((const float*)xv, (const int*)batv, ws, bstart, recB, cid, rep, sA, scid, sHT, aggB, pooledL, xls, xlsb, sbi, N, gb0, cap);
  }
}

// ---------------------------------------------------------------------------
// head: reduce 8 pooled replicas; cnt from precomputed endG; dense head.
// ---------------------------------------------------------------------------
__global__ __launch_bounds__(256) void head_kernel(
    const float* ws, const float* rep, const int* __restrict__ endG,
    void* outv, const int N)
{
  __shared__ float P[NGRAPH][HID];
  __shared__ float A[NGRAPH][HID];
  __shared__ float B[NGRAPH][HID];
  __shared__ int endL[NGRAPH];

  const int t = threadIdx.x;
  const int j = t & 63;
  const int gq = t >> 6;

  if (t < NGRAPH) endL[t] = endG[t];

  #pragma unroll
  for (int gi = 0; gi < 4; ++gi) {
    const int g = gq + gi * 4;
    float s = 0.0f;
    #pragma unroll
    for (int r = 0; r < 8; ++r)
      s += rep[(size_t)r * (NGRAPH * 64) + g * 64 + j];
    P[g][j] = s;
  }
  __syncthreads();

  {
    const float bj = ws[OFF_NB2 + j];
    #pragma unroll
    for (int gi = 0; gi < 4; ++gi) {
      const int g = gq + gi * 4;
      const float cg = (float)(endL[g] - (g ? endL[g - 1] : 0));
      float s = cg * bj;
      #pragma unroll 8
      for (int k = 0; k < HID; ++k)
        s = fmaf(P[g][k], ws[OFF_NW2 + k * HID + j], s);
      A[g][j] = s;
    }
  }
  __syncthreads();

  const int wOff[3] = {OFF_OW1, OFF_OW2, OFF_OW3};
  const int bOff[3] = {OFF_OB1, OFF_OB2, OFF_OB3};
  for (int L = 0; L < 3; ++L) {
    float (*In)[HID]  = (L & 1) ? B : A;
    float (*Out)[HID] = (L & 1) ? A : B;
    const float bj = ws[bOff[L] + j];
    #pragma unroll
    for (int gi = 0; gi < 4; ++gi) {
      const int g = gq + gi * 4;
      float s = bj;
      #pragma unroll 8
      for (int k = 0; k < HID; ++k)
        s = fmaf(In[g][k], ws[wOff[L] + k * HID + j], s);
      Out[g][j] = fmaxf(s, 0.0f);
    }
    __syncthreads();
  }

  if (t < 32) {
    const int g = t >> 1, d = t & 1;
    float s = ws[OFF_OB4 + d];
    #pragma unroll 8
    for (int k = 0; k < HID; ++k)
      s = fmaf(B[g][k], ws[OFF_OW4 + k * 2 + d], s);
    const int ft = ((const int*)(ws + OFF_FLAGS))[0];
    if (ft) ((__hip_bfloat16*)outv)[g * 2 + d] = __float2bfloat16(s);
    else    ((float*)outv)[g * 2 + d] = s;
  }
}

extern "C" void kernel_launch(void* const* d_in, const int* in_sizes, int n_in,
                              void* d_out, int out_size, void* d_ws, size_t ws_size,
                              hipStream_t stream)
{
  const void* xv   = d_in[0];
  const void* eiv  = d_in[1];
  const void* eav  = d_in[2];
  const void* batv = d_in[3];

  WPtrs wp;
  for (int a = 0; a < 16; ++a) wp.p[a] = d_in[4 + a];

  const int N = in_sizes[0];
  const int E = in_sizes[1] / 2;
  const int NB = (N + BN - 1) / BN;
  if (NB > MAXNB) return;

  float* ws   = (float*)d_ws;
  float* rep  = ws + OFF_PREP;                             // 8*1024 floats
  int* bstart = (int*)(rep + 8 * NGRAPH * 64);             // NB+1 ints
  int* endG   = bstart + NB + 1;                           // 16 ints
  int* gcnt   = endG + NGRAPH;                             // NB*NCB ints

  size_t recOffB = ((size_t)((char*)(gcnt + (size_t)NB * NCB) - (char*)d_ws) + 15) & ~(size_t)15;

  int G = -1; long long cap = 0;
  for (int g = 1; g <= 64; ++g) {
    const long long c = (long long)E / g + E / 32 + 8192;
    if (recOffB + (size_t)c * 9 <= ws_size) { G = g; cap = c; break; }
  }
  if (G < 0) return;

  ushort4* recB = (ushort4*)((char*)d_ws + recOffB);
  unsigned char* cid = (unsigned char*)(recB + cap);
  const int gsz = (NB + G - 1) / G;
  const int sblk = (NB + 3) / 4;

  (void)hipMemsetAsync(rep, 0, (size_t)(8 * NGRAPH * 64) * 4, stream);

  prep_kernel<<<1, 256, 0, stream>>>(xv, eiv, wp, ws);
  bounds_kernel<<<(N + 255) / 256, 256, 0, stream>>>(batv, ws, endG, N);
  count_kernel<<<NCB, 256, 0, stream>>>(eiv, ws, gcnt, E, NB);
  scan_tot_kernel<<<sblk, 256, 0, stream>>>(gcnt, bstart, NB);
  scan_pref_kernel<<<1, 256, 0, stream>>>(bstart, NB);
  scan_row_kernel<<<sblk, 256, 0, stream>>>(gcnt, bstart, NB);

  for (int g = 0; g < G; ++g) {
    const int gb0 = g * gsz;
    const int gb1 = (gb0 + gsz < NB) ? (gb0 + gsz) : NB;
    if (gb0 >= gb1) break;
    scatter_kernel<<<NCB, 256, 0, stream>>>(xv, eiv, eav, ws, gcnt, bstart,
                                            recB, cid, E, NB, gb0, gb1, (int)cap);
    fused_kernel<<<gb1 - gb0, 256, 0, stream>>>(xv, batv, ws, bstart, recB, cid,
                                                rep, N, gb0, (int)cap);
  }

  head_kernel<<<1, 256, 0, stream>>>(ws, rep, endG, d_out, N);
}